// Round 15
// baseline (156.605 us; speedup 1.0000x reference)
//
#include <hip/hip_runtime.h>
#include <stdint.h>

#define GRAPHS 256
#define NPG    512
#define EPG    8192
#define NTOT   (GRAPHS*NPG)

typedef __attribute__((ext_vector_type(8))) short s16x8;
typedef __attribute__((ext_vector_type(4))) float f32x4;

__device__ __forceinline__ float bf2f(unsigned short u){
  union { unsigned int i; float f; } c; c.i = ((unsigned int)u)<<16; return c.f;
}
__device__ __forceinline__ unsigned short f2bf(float f){
  union { float f; unsigned int i; } c; c.f = f;
  unsigned int r = c.i + 0x7fffu + ((c.i>>16)&1u);   // RNE
  return (unsigned short)(r>>16);
}

// ---------- CSR build + out_isqrt (blocks 0..255) ; EW1T prep (256..263) ----
// 1024 threads: 8-edge chains (was 16) and half the barrier iterations.
__global__ __launch_bounds__(1024) void k_csr(const int* __restrict__ src,
      const int* __restrict__ dst, const int* __restrict__ ntype,
      const float* __restrict__ emb, const float* __restrict__ W1,
      unsigned short* __restrict__ sorted_g, int* __restrict__ start_g,
      float* __restrict__ out_isqrt, unsigned short* __restrict__ EW1T){
  __shared__ int hist[NPG], cursor[NPG], co[NPG], cs[NPG+1];
  __shared__ unsigned short ntype_sh[NPG];
  __shared__ unsigned short sorted[EPG];
  const int tid=threadIdx.x;
  if (blockIdx.x >= GRAPHS){                     // fused EW1T = (emb@W1)^T
    const int gid = (blockIdx.x-GRAPHS)*1024 + tid;  // 8 blocks * 1024 = 8192
    const int t = gid>>7, c = gid&127;
    float acc=0.f;
    #pragma unroll 4
    for (int k=0;k<128;k++) acc += emb[t*128+k]*W1[k*128+c];
    EW1T[c*64+t]=f2bf(acc);
    return;
  }
  const int b=blockIdx.x, eb=b*EPG, nb=b*NPG;
  if (tid<NPG){ hist[tid]=0; co[tid]=0; ntype_sh[tid]=(unsigned short)ntype[nb+tid]; }
  __syncthreads();
  int4 d4[2], s4[2];
  {
    const int4* dv = (const int4*)(dst+eb);
    const int4* sv = (const int4*)(src+eb);
    #pragma unroll
    for (int j=0;j<2;j++){
      d4[j]=dv[tid + j*1024];
      s4[j]=sv[tid + j*1024];
      atomicAdd(&hist[d4[j].x&(NPG-1)],1); atomicAdd(&hist[d4[j].y&(NPG-1)],1);
      atomicAdd(&hist[d4[j].z&(NPG-1)],1); atomicAdd(&hist[d4[j].w&(NPG-1)],1);
      atomicAdd(&co[s4[j].x&(NPG-1)],1);   atomicAdd(&co[s4[j].y&(NPG-1)],1);
      atomicAdd(&co[s4[j].z&(NPG-1)],1);   atomicAdd(&co[s4[j].w&(NPG-1)],1);
    }
  }
  __syncthreads();
  if (tid<64){
    int carry=0;
    #pragma unroll
    for (int c=0;c<8;c++){
      int sc=hist[64*c+tid];
      #pragma unroll
      for (int off=1;off<64;off<<=1){ int y=__shfl_up(sc,off); if (tid>=off) sc+=y; }
      cs[64*c+tid+1]=carry+sc;
      carry+=__shfl(sc,63);
    }
    if (tid==0) cs[0]=0;
  }
  __syncthreads();
  if (tid<NPG) cursor[tid]=cs[tid];
  __syncthreads();
  #pragma unroll
  for (int j=0;j<2;j++){
    int dl, s, pos;
    dl=d4[j].x&(NPG-1); s=s4[j].x&(NPG-1);
    pos=atomicAdd(&cursor[dl],1); sorted[pos]=(unsigned short)((ntype_sh[s]<<9)|s);
    dl=d4[j].y&(NPG-1); s=s4[j].y&(NPG-1);
    pos=atomicAdd(&cursor[dl],1); sorted[pos]=(unsigned short)((ntype_sh[s]<<9)|s);
    dl=d4[j].z&(NPG-1); s=s4[j].z&(NPG-1);
    pos=atomicAdd(&cursor[dl],1); sorted[pos]=(unsigned short)((ntype_sh[s]<<9)|s);
    dl=d4[j].w&(NPG-1); s=s4[j].w&(NPG-1);
    pos=atomicAdd(&cursor[dl],1); sorted[pos]=(unsigned short)((ntype_sh[s]<<9)|s);
  }
  __syncthreads();
  for (int i=tid;i<EPG/2;i+=1024)
    ((unsigned int*)(sorted_g+(size_t)eb))[i] = ((const unsigned int*)sorted)[i];
  if (tid<NPG){
    start_g[b*(NPG+1)+tid]=cs[tid];
    int a=co[tid]; if(a<1)a=1;
    out_isqrt[nb+tid]=rsqrtf((float)a);
  }
  if (tid==0) start_g[b*(NPG+1)+NPG]=cs[NPG];
}

// ---------- layer-1: S-histogram + MFMA(S_hi/lo @ EW1) ----------------------
// block = (graph, half: 256 dst rows), 512 thr. S-scatter: 2 threads/dst with
// disjoint type-parity -> RMW chain depth halves, no races.
// Output h1 in MFMA-B-fragment order (R13 win).
#define A1_LDS 73232   // S f32[256][68] | wsc[512] | sstart[257] | bsh[128]
__global__ __launch_bounds__(512) void k_agg1(
      const unsigned short* __restrict__ sorted_g, const int* __restrict__ start_g,
      const unsigned short* __restrict__ EW1T, const float* __restrict__ out_isqrt,
      const float* __restrict__ b1, unsigned short* __restrict__ h1F){
  extern __shared__ char smem[];
  float* S      = (float*)(smem);               // [256][68]
  float* wsc    = (float*)(smem + 69632);       // [512]
  int*   sstart = (int*)  (smem + 71680);       // [257]
  float* bsh    = (float*)(smem + 72720);       // [128]
  const int bid=blockIdx.x, b=bid>>1, half=bid&1;
  const int v0=half*256, nb=b*NPG, tid=threadIdx.x;
  for (int i=tid; i<(256*68)/4; i+=512) ((f32x4*)S)[i]=(f32x4){0.f,0.f,0.f,0.f};
  for (int i=tid; i<NPG; i+=512) wsc[i]=out_isqrt[nb+i];
  for (int i=tid; i<257; i+=512) sstart[i]=start_g[b*(NPG+1)+v0+i];
  if (tid<128) bsh[tid]=b1[tid];
  __syncthreads();
  {                                             // 2 thr/dst, parity-partitioned
    const int d = tid>>1, q = tid&1;
    const int beg=sstart[d], end=sstart[d+1];
    float* Sd = S + d*68;
    const unsigned short* sg = sorted_g + (size_t)b*EPG;
    for (int i=beg;i<end;++i){
      const int ent = sg[i];
      const int t = ent>>9;
      if ((t&1)==q) Sd[t] += wsc[ent&511];
    }
  }
  __syncthreads();
  const int wave=tid>>6, lane=tid&63, l16=lane&15, quad=lane>>4;
  f32x4 acc[2][8];
  #pragma unroll
  for (int rt=0;rt<2;rt++)
    #pragma unroll
    for (int nt=0;nt<8;nt++) acc[rt][nt]=(f32x4){0.f,0.f,0.f,0.f};
  #pragma unroll
  for (int ks=0; ks<4; ++ks){                   // ks 0,1 = hi; 2,3 = lo
    const int kc = (ks&1)*32 + quad*8;
    s16x8 a[2];
    #pragma unroll
    for (int rt=0;rt<2;rt++){
      const int m = (wave*2+rt)*16 + l16;
      const float* sp = &S[m*68 + kc];
      f32x4 va = *(const f32x4*)sp;
      f32x4 vb = *(const f32x4*)(sp+4);
      union { s16x8 v; unsigned short u[8]; } pk;
      #pragma unroll
      for (int j=0;j<8;j++){
        const float f = (j<4)? va[j] : vb[j-4];
        const unsigned short hi = f2bf(f);
        pk.u[j] = (ks<2) ? hi : f2bf(f - bf2f(hi));
      }
      a[rt]=pk.v;
    }
    #pragma unroll
    for (int nt=0;nt<8;nt++){
      s16x8 bfr=__builtin_bit_cast(s16x8,
          *(const uint4*)(EW1T + (size_t)(nt*16+l16)*64 + kc));
      #pragma unroll
      for (int rt=0;rt<2;rt++)
        acc[rt][nt]=__builtin_amdgcn_mfma_f32_16x16x32_bf16(a[rt],bfr,acc[rt][nt],0,0,0);
    }
  }
  #pragma unroll
  for (int rt=0;rt<2;rt++){
    const int W = wave*2+rt;                    // m-tile in [0,16) within half
    const int mloc = W*16 + quad*4;
    float isq[4], os[4];
    #pragma unroll
    for (int r=0;r<4;r++){
      int d = sstart[mloc+r+1]-sstart[mloc+r]; if (d<1) d=1;
      isq[r]=rsqrtf((float)d);
      os[r]=wsc[v0+mloc+r];
    }
    const int ks2 = half*8 + (W>>1);
    const int q2  = ((W&1)<<1) | (quad>>1);
    const int j0  = (quad&1)*4;
    #pragma unroll
    for (int nt=0;nt<8;nt++){
      const int col = nt*16+l16;
      const float bb = bsh[col];
      ushort4 st;
      float v;
      v = fmaxf(acc[rt][nt][0]*isq[0]+bb,0.f)*os[0]; st.x=f2bf(v);
      v = fmaxf(acc[rt][nt][1]*isq[1]+bb,0.f)*os[1]; st.y=f2bf(v);
      v = fmaxf(acc[rt][nt][2]*isq[2]+bb,0.f)*os[2]; st.z=f2bf(v);
      v = fmaxf(acc[rt][nt][3]*isq[3]+bb,0.f)*os[3]; st.w=f2bf(v);
      const size_t off = ((((size_t)b*16 + ks2)*8 + nt)*64 + q2*16 + l16)*8 + j0;
      *(ushort4*)(h1F + off) = st;
    }
  }
}

// ---------- layer-2: A(u8 counts) @ h1F via MFMA -> M1F ---------------------
// block = (graph, 128-dst tile), 512 thr, 67 KB LDS -> 2 blocks/CU.
// Coalesced h1F B-loads (R13); M1F stored in gemm2-A-fragment order (R14).
#define A2_LDS 67080   // A u8[128][520] | sstart[129]
__global__ __launch_bounds__(512) void k_agg2(
      const unsigned short* __restrict__ sorted_g, const int* __restrict__ start_g,
      const unsigned short* __restrict__ h1F, unsigned short* __restrict__ M1F){
  extern __shared__ char smem[];
  unsigned char* A = (unsigned char*)smem;      // [128][520]
  unsigned int* A32 = (unsigned int*)smem;
  int* sstart = (int*)(smem + 66560);           // [129]
  const int bid=blockIdx.x;
  const int b  = ((bid>>5)<<3) | (bid&7);       // graph (XCD swizzle)
  const int dt = (bid>>3)&3;                    // dst tile
  const int v0=dt*128, tid=threadIdx.x;
  for (int i=tid; i<66560/16; i+=512) ((uint4*)smem)[i]=(uint4){0u,0u,0u,0u};
  for (int i=tid; i<129; i+=512) sstart[i]=start_g[b*(NPG+1)+v0+i];
  __syncthreads();
  {                                             // parallel count scatter: 4 thr/dst
    const int d = tid>>2, q = tid&3;
    const int beg=sstart[d], end=sstart[d+1], len=end-beg;
    const int qb = beg + ((len*q)>>2), qe = beg + ((len*(q+1))>>2);
    const unsigned short* sg = sorted_g + (size_t)b*EPG;
    const int rowbase = d*130;
    for (int i=qb;i<qe;++i){
      const int s = sg[i]&511;
      atomicAdd(&A32[rowbase + (s>>2)], 1u<<((s&3)*8));
    }
  }
  __syncthreads();
  const int wave=tid>>6, lane=tid&63, l16=lane&15, quad=lane>>4;
  const int mg=wave>>1, ng=wave&1;              // 8 m-tiles x 8 n-tiles total
  f32x4 acc[2][4];
  #pragma unroll
  for (int rt=0;rt<2;rt++)
    #pragma unroll
    for (int ct=0;ct<4;ct++) acc[rt][ct]=(f32x4){0.f,0.f,0.f,0.f};

  const uint4* bp[4];                           // coalesced fragment pointers
  #pragma unroll
  for (int ct=0;ct<4;ct++)
    bp[ct] = (const uint4*)h1F + (((size_t)b*16)*8 + (ng*4+ct))*64 + lane;
  const unsigned char* Ab[2];
  #pragma unroll
  for (int rt=0;rt<2;rt++)
    Ab[rt] = A + ((mg*2+rt)*16 + l16)*520 + quad*8;

  #pragma unroll 2
  for (int ks=0; ks<16; ++ks){
    uint4 bq[4];
    #pragma unroll
    for (int ct=0;ct<4;ct++) bq[ct] = bp[ct][(size_t)ks*512];  // ks stride: 8ct*64
    s16x8 afr[2];
    #pragma unroll
    for (int rt=0;rt<2;rt++){
      const uint2 aw = *(const uint2*)(Ab[rt] + ks*32);
      union { s16x8 v; unsigned short u[8]; } pk;
      #pragma unroll
      for (int j=0;j<4;j++){
        const float f0 = (float)((aw.x>>(8*j))&0xffu);   // exact small ints
        const float f1 = (float)((aw.y>>(8*j))&0xffu);
        pk.u[j]   = (unsigned short)(__builtin_bit_cast(unsigned int, f0)>>16);
        pk.u[j+4] = (unsigned short)(__builtin_bit_cast(unsigned int, f1)>>16);
      }
      afr[rt]=pk.v;
    }
    #pragma unroll
    for (int rt=0;rt<2;rt++)
      #pragma unroll
      for (int ct=0;ct<4;ct++)
        acc[rt][ct]=__builtin_amdgcn_mfma_f32_16x16x32_bf16(afr[rt],
            __builtin_bit_cast(s16x8, bq[ct]), acc[rt][ct],0,0,0);
  }
  #pragma unroll
  for (int rt=0;rt<2;rt++){
    const int mloc=(mg*2+rt)*16 + quad*4;
    const int M = dt*8 + mg*2 + rt;
    float isq[4];
    #pragma unroll
    for (int r=0;r<4;r++){
      int d=sstart[mloc+r+1]-sstart[mloc+r]; if (d<1) d=1;
      isq[r]=rsqrtf((float)d);
    }
    #pragma unroll
    for (int ct=0;ct<4;ct++){
      const int ks2   = ng*2 + (ct>>1);
      const int quad2 = ((ct&1)<<1) | (l16>>3);
      const int j     = l16&7;
      unsigned short* base = M1F
          + ((((size_t)b*32+M)*4+ks2)*64 + quad2*16)*8 + j;
      #pragma unroll
      for (int r=0;r<4;r++)
        base[(size_t)(quad*4+r)*8] = f2bf(acc[rt][ct][r]*isq[r]);
    }
  }
}

// ---------- final GEMM: relu(M1F @ W2 + b2), fused per-graph mean -> out ----
// M1F fragment loads hoisted to kernel entry: latency hides behind W2 staging.
__global__ __launch_bounds__(512) void k_gemm2(const unsigned short* __restrict__ M1F,
      const float* __restrict__ W2, const float* __restrict__ b2,
      float* __restrict__ out){
  __shared__ __align__(16) unsigned short WT[128][136];  // WT[n][k]
  __shared__ float bsh[128];
  __shared__ float colpart[8][128];
  const int b=blockIdx.x, tid=threadIdx.x;
  const int wave=tid>>6, lane=tid&63, l16=lane&15, quad=lane>>4;
  uint4 apre[2][2][4];                           // [chunk][rt][ks] prefetch
  #pragma unroll
  for (int chunk=0;chunk<2;chunk++)
    #pragma unroll
    for (int rt=0;rt<2;rt++)
      #pragma unroll
      for (int ks=0;ks<4;ks++){
        const int M = wave*4 + chunk*2 + rt;
        apre[chunk][rt][ks] = *(const uint4*)(M1F
            + ((((size_t)b*32+M)*4+ks)*64 + lane)*8);
      }
  for (int idx=tid; idx<128*128; idx+=512){
    const int k=idx>>7, n=idx&127;
    WT[n][k]=f2bf(W2[idx]);
  }
  if (tid<128) bsh[tid]=b2[tid];
  __syncthreads();
  float p[8];
  #pragma unroll
  for (int i=0;i<8;i++) p[i]=0.f;
  #pragma unroll
  for (int chunk=0; chunk<2; ++chunk){
    f32x4 acc[2][8];
    #pragma unroll
    for (int rt=0;rt<2;rt++)
      #pragma unroll
      for (int ct=0;ct<8;ct++) acc[rt][ct]=(f32x4){0.f,0.f,0.f,0.f};
    #pragma unroll
    for (int ks=0;ks<4;ks++){
      s16x8 bf[8];
      #pragma unroll
      for (int ct=0;ct<8;ct++)
        bf[ct]=__builtin_bit_cast(s16x8, *(const uint4*)&WT[ct*16+l16][ks*32+quad*8]);
      #pragma unroll
      for (int rt=0;rt<2;rt++){
        const s16x8 a = __builtin_bit_cast(s16x8, apre[chunk][rt][ks]);
        #pragma unroll
        for (int ct=0;ct<8;ct++)
          acc[rt][ct]=__builtin_amdgcn_mfma_f32_16x16x32_bf16(a,bf[ct],acc[rt][ct],0,0,0);
      }
    }
    #pragma unroll
    for (int rt=0;rt<2;rt++)
      #pragma unroll
      for (int ct=0;ct<8;ct++)
        #pragma unroll
        for (int r=0;r<4;r++){
          const int col=ct*16+l16;
          p[ct] += fmaxf(acc[rt][ct][r]+bsh[col],0.f);
        }
  }
  #pragma unroll
  for (int ct=0;ct<8;ct++){
    p[ct] += __shfl_xor(p[ct],16);
    p[ct] += __shfl_xor(p[ct],32);
  }
  if (quad==0){
    #pragma unroll
    for (int ct=0;ct<8;ct++) colpart[wave][ct*16+l16]=p[ct];
  }
  __syncthreads();
  if (tid<128){
    float s=0.f;
    #pragma unroll
    for (int w=0;w<8;w++) s+=colpart[w][tid];
    out[b*128+tid]=s*(1.f/512.f);
  }
}

extern "C" void kernel_launch(void* const* d_in, const int* in_sizes, int n_in,
                              void* d_out, int out_size, void* d_ws, size_t ws_size,
                              hipStream_t stream){
  const int* node_feat = (const int*)d_in[0];
  const int* src = (const int*)d_in[1];
  const int* dst = (const int*)d_in[2];
  const float* emb = (const float*)d_in[3];
  const float* W1  = (const float*)d_in[4];
  const float* b1  = (const float*)d_in[5];
  const float* W2  = (const float*)d_in[6];
  const float* b2  = (const float*)d_in[7];

  char* ws = (char*)d_ws;
  float* out_isqrt        = (float*)(ws);                          // 524288 B
  int* start_g            = (int*)(ws + 524288);                   // 525312 B
  unsigned short* sorted_g= (unsigned short*)(ws + 1049600);       // 4194304 B
  unsigned short* EW1T    = (unsigned short*)(ws + 5243904);       // 16384 B
  unsigned short* h1F     = (unsigned short*)(ws + 5260288);       // 33554432 B
  unsigned short* M1F     = (unsigned short*)(ws + 38814720);      // 33554432 B

  (void)hipFuncSetAttribute(reinterpret_cast<const void*>(&k_agg1),
        hipFuncAttributeMaxDynamicSharedMemorySize, A1_LDS);
  (void)hipFuncSetAttribute(reinterpret_cast<const void*>(&k_agg2),
        hipFuncAttributeMaxDynamicSharedMemorySize, A2_LDS);

  k_csr<<<GRAPHS+8,1024,0,stream>>>(src,dst,node_feat,emb,W1,
        sorted_g,start_g,out_isqrt,EW1T);
  k_agg1<<<GRAPHS*2,512,A1_LDS,stream>>>(sorted_g,start_g,EW1T,out_isqrt,b1,h1F);
  k_agg2<<<GRAPHS*4,512,A2_LDS,stream>>>(sorted_g,start_g,h1F,M1F);
  k_gemm2<<<GRAPHS,512,0,stream>>>(M1F,W2,b2,(float*)d_out);
}

// Round 16
// 155.221 us; speedup vs baseline: 1.0089x; 1.0089x over previous
//
#include <hip/hip_runtime.h>
#include <stdint.h>

#define GRAPHS 256
#define NPG    512
#define EPG    8192
#define NTOT   (GRAPHS*NPG)

typedef __attribute__((ext_vector_type(8))) short s16x8;
typedef __attribute__((ext_vector_type(4))) float f32x4;

__device__ __forceinline__ float bf2f(unsigned short u){
  union { unsigned int i; float f; } c; c.i = ((unsigned int)u)<<16; return c.f;
}
__device__ __forceinline__ unsigned short f2bf(float f){
  union { float f; unsigned int i; } c; c.f = f;
  unsigned int r = c.i + 0x7fffu + ((c.i>>16)&1u);   // RNE
  return (unsigned short)(r>>16);
}

// ---------- fused: CSR build + EW1 + layer-1 agg (one block per graph) ------
// Phase A: emb->LDS, EW1=emb@W1 ->LDS(bf16, stride 72), histogram+scan+
//          counting sort into LDS sorted[] (flushed once to global for agg2).
// Phase B (x2 halves): S-scatter from LDS sorted (short chains), MFMA
//          S_hi/lo @ EW1, h1F fragment-order epilogue (R13 layout).
// LDS map: S f32[256][68] @0 (phase-A alias: hist@0 co@2048 cursor@4096
//          ntype_sh@6144 emb_sh f32[8192]@8192) | sorted u16[8192]@69632 |
//          ew u16[128*72]@86016 | cs int[513]@104448 | wsc@106504 | bsh@108552
#define BUILD_LDS 109568
__global__ __launch_bounds__(512) void k_build(const int* __restrict__ src,
      const int* __restrict__ dst, const int* __restrict__ ntype,
      const float* __restrict__ emb, const float* __restrict__ W1,
      const float* __restrict__ b1, unsigned short* __restrict__ sorted_g,
      int* __restrict__ start_g, unsigned short* __restrict__ h1F){
  extern __shared__ char smem[];
  float* S        = (float*)(smem);                   // [256][68] (phase B)
  int*   hist     = (int*)(smem);                     // [512] (phase A alias)
  int*   co       = (int*)(smem + 2048);              // [512]
  int*   cursor   = (int*)(smem + 4096);              // [512]
  unsigned short* ntype_sh = (unsigned short*)(smem + 6144);  // [512]
  float* emb_sh   = (float*)(smem + 8192);            // [64*128] (phase A)
  unsigned short* sorted = (unsigned short*)(smem + 69632);   // [8192]
  unsigned short* ew     = (unsigned short*)(smem + 86016);   // [128*72]
  int*   cs       = (int*)(smem + 104448);            // [513]
  float* wsc      = (float*)(smem + 106504);          // [512]
  float* bsh      = (float*)(smem + 108552);          // [128]
  const int b=blockIdx.x, tid=threadIdx.x, eb=b*EPG, nb=b*NPG;

  // ---- phase A: init + stage emb + edges in regs ----
  hist[tid]=0; co[tid]=0; ntype_sh[tid]=(unsigned short)ntype[nb+tid];
  for (int i=tid; i<8192/4; i+=512) ((f32x4*)emb_sh)[i]=((const f32x4*)emb)[i];
  if (tid<128) bsh[tid]=b1[tid];
  int4 d4[4], s4[4];
  {
    const int4* dv = (const int4*)(dst+eb);
    const int4* sv = (const int4*)(src+eb);
    #pragma unroll
    for (int j=0;j<4;j++){ d4[j]=dv[tid + j*512]; s4[j]=sv[tid + j*512]; }
  }
  __syncthreads();
  // ---- EW1 = emb @ W1 -> ew[c*72+t] bf16 (lane-uniform emb_sh broadcasts) --
  {
    const int c = tid&127, tg = tid>>7;               // tg wave-uniform
    float acc[16];
    #pragma unroll
    for (int i=0;i<16;i++) acc[i]=0.f;
    for (int k=0;k<128;k++){
      const float w1 = W1[k*128+c];
      #pragma unroll
      for (int i=0;i<16;i++) acc[i] += emb_sh[(tg*16+i)*128 + k]*w1;
    }
    #pragma unroll
    for (int i=0;i<16;i++) ew[c*72 + tg*16+i] = f2bf(acc[i]);
  }
  // ---- histogram ----
  #pragma unroll
  for (int j=0;j<4;j++){
    atomicAdd(&hist[d4[j].x&(NPG-1)],1); atomicAdd(&hist[d4[j].y&(NPG-1)],1);
    atomicAdd(&hist[d4[j].z&(NPG-1)],1); atomicAdd(&hist[d4[j].w&(NPG-1)],1);
    atomicAdd(&co[s4[j].x&(NPG-1)],1);   atomicAdd(&co[s4[j].y&(NPG-1)],1);
    atomicAdd(&co[s4[j].z&(NPG-1)],1);   atomicAdd(&co[s4[j].w&(NPG-1)],1);
  }
  __syncthreads();
  if (tid<64){                                        // wave-0 exclusive scan
    int carry=0;
    #pragma unroll
    for (int c2=0;c2<8;c2++){
      int sc=hist[64*c2+tid];
      #pragma unroll
      for (int off=1;off<64;off<<=1){ int y=__shfl_up(sc,off); if (tid>=off) sc+=y; }
      cs[64*c2+tid+1]=carry+sc;
      carry+=__shfl(sc,63);
    }
    if (tid==0) cs[0]=0;
  }
  __syncthreads();
  cursor[tid]=cs[tid];
  __syncthreads();
  #pragma unroll
  for (int j=0;j<4;j++){
    int dl, s, pos;
    dl=d4[j].x&(NPG-1); s=s4[j].x&(NPG-1);
    pos=atomicAdd(&cursor[dl],1); sorted[pos]=(unsigned short)((ntype_sh[s]<<9)|s);
    dl=d4[j].y&(NPG-1); s=s4[j].y&(NPG-1);
    pos=atomicAdd(&cursor[dl],1); sorted[pos]=(unsigned short)((ntype_sh[s]<<9)|s);
    dl=d4[j].z&(NPG-1); s=s4[j].z&(NPG-1);
    pos=atomicAdd(&cursor[dl],1); sorted[pos]=(unsigned short)((ntype_sh[s]<<9)|s);
    dl=d4[j].w&(NPG-1); s=s4[j].w&(NPG-1);
    pos=atomicAdd(&cursor[dl],1); sorted[pos]=(unsigned short)((ntype_sh[s]<<9)|s);
  }
  __syncthreads();
  // flush sorted + start to global (for agg2); wsc from co (S alias dies here)
  for (int i=tid;i<EPG/2;i+=512)
    ((unsigned int*)(sorted_g+(size_t)eb))[i] = ((const unsigned int*)sorted)[i];
  start_g[b*(NPG+1)+tid]=cs[tid];
  if (tid==0) start_g[b*(NPG+1)+NPG]=cs[NPG];
  {
    int a=co[tid]; if(a<1)a=1;
    wsc[tid]=rsqrtf((float)a);
  }
  __syncthreads();

  const int wave=tid>>6, lane=tid&63, l16=lane&15, quad=lane>>4;
  // ---- phase B: per half, S-scatter (LDS chains) + MFMA + h1F epilogue ----
  for (int half=0; half<2; ++half){
    const int v0=half*256;
    __syncthreads();                                  // prior S readers done
    for (int i=tid; i<(256*68)/4; i+=512) ((f32x4*)S)[i]=(f32x4){0.f,0.f,0.f,0.f};
    __syncthreads();
    if (tid<256){                                     // thread-per-dst scatter
      const int d = v0 + tid;
      const int beg=cs[d], end=cs[d+1];
      float* Sd = S + tid*68;
      for (int i=beg;i<end;++i){
        const int ent = sorted[i];
        Sd[ent>>9] += wsc[ent&511];
      }
    }
    __syncthreads();
    f32x4 acc[2][8];
    #pragma unroll
    for (int rt=0;rt<2;rt++)
      #pragma unroll
      for (int nt=0;nt<8;nt++) acc[rt][nt]=(f32x4){0.f,0.f,0.f,0.f};
    #pragma unroll
    for (int ks=0; ks<4; ++ks){                       // ks 0,1 = hi; 2,3 = lo
      const int kc = (ks&1)*32 + quad*8;
      s16x8 a[2];
      #pragma unroll
      for (int rt=0;rt<2;rt++){
        const int m = (wave*2+rt)*16 + l16;
        const float* sp = &S[m*68 + kc];
        f32x4 va = *(const f32x4*)sp;
        f32x4 vb = *(const f32x4*)(sp+4);
        union { s16x8 v; unsigned short u[8]; } pk;
        #pragma unroll
        for (int j=0;j<8;j++){
          const float f = (j<4)? va[j] : vb[j-4];
          const unsigned short hi = f2bf(f);
          pk.u[j] = (ks<2) ? hi : f2bf(f - bf2f(hi));
        }
        a[rt]=pk.v;
      }
      #pragma unroll
      for (int nt=0;nt<8;nt++){
        s16x8 bfr=__builtin_bit_cast(s16x8,
            *(const uint4*)(ew + (nt*16+l16)*72 + kc));
        #pragma unroll
        for (int rt=0;rt<2;rt++)
          acc[rt][nt]=__builtin_amdgcn_mfma_f32_16x16x32_bf16(a[rt],bfr,acc[rt][nt],0,0,0);
      }
    }
    #pragma unroll
    for (int rt=0;rt<2;rt++){
      const int W = wave*2+rt;                        // m-tile in [0,16)
      const int mloc = W*16 + quad*4;
      float isq[4], os[4];
      #pragma unroll
      for (int r=0;r<4;r++){
        int d = cs[v0+mloc+r+1]-cs[v0+mloc+r]; if (d<1) d=1;
        isq[r]=rsqrtf((float)d);
        os[r]=wsc[v0+mloc+r];
      }
      const int ks2 = half*8 + (W>>1);
      const int q2  = ((W&1)<<1) | (quad>>1);
      const int j0  = (quad&1)*4;
      #pragma unroll
      for (int nt=0;nt<8;nt++){
        const int col = nt*16+l16;
        const float bb = bsh[col];
        ushort4 st;
        float v;
        v = fmaxf(acc[rt][nt][0]*isq[0]+bb,0.f)*os[0]; st.x=f2bf(v);
        v = fmaxf(acc[rt][nt][1]*isq[1]+bb,0.f)*os[1]; st.y=f2bf(v);
        v = fmaxf(acc[rt][nt][2]*isq[2]+bb,0.f)*os[2]; st.z=f2bf(v);
        v = fmaxf(acc[rt][nt][3]*isq[3]+bb,0.f)*os[3]; st.w=f2bf(v);
        const size_t off = ((((size_t)b*16 + ks2)*8 + nt)*64 + q2*16 + l16)*8 + j0;
        *(ushort4*)(h1F + off) = st;
      }
    }
  }
}

// ---------- layer-2: A(u8 counts) @ h1F via MFMA -> M1F (R14, unchanged) ----
#define A2_LDS 67080   // A u8[128][520] | sstart[129]
__global__ __launch_bounds__(512) void k_agg2(
      const unsigned short* __restrict__ sorted_g, const int* __restrict__ start_g,
      const unsigned short* __restrict__ h1F, unsigned short* __restrict__ M1F){
  extern __shared__ char smem[];
  unsigned char* A = (unsigned char*)smem;      // [128][520]
  unsigned int* A32 = (unsigned int*)smem;
  int* sstart = (int*)(smem + 66560);           // [129]
  const int bid=blockIdx.x;
  const int b  = ((bid>>5)<<3) | (bid&7);       // graph (XCD swizzle)
  const int dt = (bid>>3)&3;                    // dst tile
  const int v0=dt*128, tid=threadIdx.x;
  for (int i=tid; i<66560/16; i+=512) ((uint4*)smem)[i]=(uint4){0u,0u,0u,0u};
  for (int i=tid; i<129; i+=512) sstart[i]=start_g[b*(NPG+1)+v0+i];
  __syncthreads();
  {                                             // parallel count scatter: 4 thr/dst
    const int d = tid>>2, q = tid&3;
    const int beg=sstart[d], end=sstart[d+1], len=end-beg;
    const int qb = beg + ((len*q)>>2), qe = beg + ((len*(q+1))>>2);
    const unsigned short* sg = sorted_g + (size_t)b*EPG;
    const int rowbase = d*130;
    for (int i=qb;i<qe;++i){
      const int s = sg[i]&511;
      atomicAdd(&A32[rowbase + (s>>2)], 1u<<((s&3)*8));
    }
  }
  __syncthreads();
  const int wave=tid>>6, lane=tid&63, l16=lane&15, quad=lane>>4;
  const int mg=wave>>1, ng=wave&1;              // 8 m-tiles x 8 n-tiles total
  f32x4 acc[2][4];
  #pragma unroll
  for (int rt=0;rt<2;rt++)
    #pragma unroll
    for (int ct=0;ct<4;ct++) acc[rt][ct]=(f32x4){0.f,0.f,0.f,0.f};
  const uint4* bp[4];                           // coalesced fragment pointers
  #pragma unroll
  for (int ct=0;ct<4;ct++)
    bp[ct] = (const uint4*)h1F + (((size_t)b*16)*8 + (ng*4+ct))*64 + lane;
  const unsigned char* Ab[2];
  #pragma unroll
  for (int rt=0;rt<2;rt++)
    Ab[rt] = A + ((mg*2+rt)*16 + l16)*520 + quad*8;
  #pragma unroll 2
  for (int ks=0; ks<16; ++ks){
    uint4 bq[4];
    #pragma unroll
    for (int ct=0;ct<4;ct++) bq[ct] = bp[ct][(size_t)ks*512];
    s16x8 afr[2];
    #pragma unroll
    for (int rt=0;rt<2;rt++){
      const uint2 aw = *(const uint2*)(Ab[rt] + ks*32);
      union { s16x8 v; unsigned short u[8]; } pk;
      #pragma unroll
      for (int j=0;j<4;j++){
        const float f0 = (float)((aw.x>>(8*j))&0xffu);
        const float f1 = (float)((aw.y>>(8*j))&0xffu);
        pk.u[j]   = (unsigned short)(__builtin_bit_cast(unsigned int, f0)>>16);
        pk.u[j+4] = (unsigned short)(__builtin_bit_cast(unsigned int, f1)>>16);
      }
      afr[rt]=pk.v;
    }
    #pragma unroll
    for (int rt=0;rt<2;rt++)
      #pragma unroll
      for (int ct=0;ct<4;ct++)
        acc[rt][ct]=__builtin_amdgcn_mfma_f32_16x16x32_bf16(afr[rt],
            __builtin_bit_cast(s16x8, bq[ct]), acc[rt][ct],0,0,0);
  }
  #pragma unroll
  for (int rt=0;rt<2;rt++){
    const int mloc=(mg*2+rt)*16 + quad*4;
    const int M = dt*8 + mg*2 + rt;
    float isq[4];
    #pragma unroll
    for (int r=0;r<4;r++){
      int d=sstart[mloc+r+1]-sstart[mloc+r]; if (d<1) d=1;
      isq[r]=rsqrtf((float)d);
    }
    #pragma unroll
    for (int ct=0;ct<4;ct++){
      const int ks2   = ng*2 + (ct>>1);
      const int quad2 = ((ct&1)<<1) | (l16>>3);
      const int j     = l16&7;
      unsigned short* base = M1F
          + ((((size_t)b*32+M)*4+ks2)*64 + quad2*16)*8 + j;
      #pragma unroll
      for (int r=0;r<4;r++)
        base[(size_t)(quad*4+r)*8] = f2bf(acc[rt][ct][r]*isq[r]);
    }
  }
}

// ---------- final GEMM: relu(M1F @ W2 + b2), fused mean (R14, unchanged) ----
__global__ __launch_bounds__(512) void k_gemm2(const unsigned short* __restrict__ M1F,
      const float* __restrict__ W2, const float* __restrict__ b2,
      float* __restrict__ out){
  __shared__ __align__(16) unsigned short WT[128][136];  // WT[n][k]
  __shared__ float bsh[128];
  __shared__ float colpart[8][128];
  const int b=blockIdx.x, tid=threadIdx.x;
  for (int idx=tid; idx<128*128; idx+=512){
    const int k=idx>>7, n=idx&127;
    WT[n][k]=f2bf(W2[idx]);
  }
  if (tid<128) bsh[tid]=b2[tid];
  __syncthreads();
  const int wave=tid>>6, lane=tid&63, l16=lane&15, quad=lane>>4;
  float p[8];
  #pragma unroll
  for (int i=0;i<8;i++) p[i]=0.f;
  for (int chunk=0; chunk<2; ++chunk){
    f32x4 acc[2][8];
    #pragma unroll
    for (int rt=0;rt<2;rt++)
      #pragma unroll
      for (int ct=0;ct<8;ct++) acc[rt][ct]=(f32x4){0.f,0.f,0.f,0.f};
    #pragma unroll
    for (int ks=0;ks<4;ks++){
      s16x8 a[2], bf[8];
      #pragma unroll
      for (int rt=0;rt<2;rt++){
        const int M = wave*4 + chunk*2 + rt;
        a[rt]=__builtin_bit_cast(s16x8, *(const uint4*)(M1F
            + ((((size_t)b*32+M)*4+ks)*64 + lane)*8));
      }
      #pragma unroll
      for (int ct=0;ct<8;ct++)
        bf[ct]=__builtin_bit_cast(s16x8, *(const uint4*)&WT[ct*16+l16][ks*32+quad*8]);
      #pragma unroll
      for (int rt=0;rt<2;rt++)
        #pragma unroll
        for (int ct=0;ct<8;ct++)
          acc[rt][ct]=__builtin_amdgcn_mfma_f32_16x16x32_bf16(a[rt],bf[ct],acc[rt][ct],0,0,0);
    }
    #pragma unroll
    for (int rt=0;rt<2;rt++)
      #pragma unroll
      for (int ct=0;ct<8;ct++)
        #pragma unroll
        for (int r=0;r<4;r++){
          const int col=ct*16+l16;
          p[ct] += fmaxf(acc[rt][ct][r]+bsh[col],0.f);
        }
  }
  #pragma unroll
  for (int ct=0;ct<8;ct++){
    p[ct] += __shfl_xor(p[ct],16);
    p[ct] += __shfl_xor(p[ct],32);
  }
  if (quad==0){
    #pragma unroll
    for (int ct=0;ct<8;ct++) colpart[wave][ct*16+l16]=p[ct];
  }
  __syncthreads();
  if (tid<128){
    float s=0.f;
    #pragma unroll
    for (int w=0;w<8;w++) s+=colpart[w][tid];
    out[b*128+tid]=s*(1.f/512.f);
  }
}

extern "C" void kernel_launch(void* const* d_in, const int* in_sizes, int n_in,
                              void* d_out, int out_size, void* d_ws, size_t ws_size,
                              hipStream_t stream){
  const int* node_feat = (const int*)d_in[0];
  const int* src = (const int*)d_in[1];
  const int* dst = (const int*)d_in[2];
  const float* emb = (const float*)d_in[3];
  const float* W1  = (const float*)d_in[4];
  const float* b1  = (const float*)d_in[5];
  const float* W2  = (const float*)d_in[6];
  const float* b2  = (const float*)d_in[7];

  char* ws = (char*)d_ws;
  int* start_g            = (int*)(ws);                            // 525312 B
  unsigned short* sorted_g= (unsigned short*)(ws + 525312);        // 4194304 B
  unsigned short* h1F     = (unsigned short*)(ws + 4719616);       // 33554432 B
  unsigned short* M1F     = (unsigned short*)(ws + 38274048);      // 33554432 B

  (void)hipFuncSetAttribute(reinterpret_cast<const void*>(&k_build),
        hipFuncAttributeMaxDynamicSharedMemorySize, BUILD_LDS);
  (void)hipFuncSetAttribute(reinterpret_cast<const void*>(&k_agg2),
        hipFuncAttributeMaxDynamicSharedMemorySize, A2_LDS);

  k_build<<<GRAPHS,512,BUILD_LDS,stream>>>(src,dst,node_feat,emb,W1,b1,
        sorted_g,start_g,h1F);
  k_agg2<<<GRAPHS*4,512,A2_LDS,stream>>>(sorted_g,start_g,h1F,M1F);
  k_gemm2<<<GRAPHS,512,0,stream>>>(M1F,W2,b2,(float*)d_out);
}

// Round 17
// 151.138 us; speedup vs baseline: 1.0362x; 1.0270x over previous
//
#include <hip/hip_runtime.h>
#include <stdint.h>

#define GRAPHS 256
#define NPG    512
#define EPG    8192
#define NTOT   (GRAPHS*NPG)

typedef __attribute__((ext_vector_type(8))) short s16x8;
typedef __attribute__((ext_vector_type(4))) float f32x4;

__device__ __forceinline__ float bf2f(unsigned short u){
  union { unsigned int i; float f; } c; c.i = ((unsigned int)u)<<16; return c.f;
}
__device__ __forceinline__ unsigned short f2bf(float f){
  union { float f; unsigned int i; } c; c.f = f;
  unsigned int r = c.i + 0x7fffu + ((c.i>>16)&1u);   // RNE
  return (unsigned short)(r>>16);
}

// ---------- CSR build + out_isqrt (blocks 0..255) ; prep (256..303) ---------
// Extra blocks: EW1T = (emb@W1)^T bf16 (8192 elems) and W2T[n][k] bf16
// (16384 elems) so gemm2 stages pre-converted weights with uint4 copies.
__global__ __launch_bounds__(512) void k_csr(const int* __restrict__ src,
      const int* __restrict__ dst, const int* __restrict__ ntype,
      const float* __restrict__ emb, const float* __restrict__ W1,
      const float* __restrict__ W2,
      unsigned short* __restrict__ sorted_g, int* __restrict__ start_g,
      float* __restrict__ out_isqrt, unsigned short* __restrict__ EW1T,
      unsigned short* __restrict__ W2T){
  __shared__ int hist[NPG], cursor[NPG], co[NPG], cs[NPG+1];
  __shared__ unsigned short ntype_sh[NPG];
  __shared__ unsigned short sorted[EPG];
  const int tid=threadIdx.x;
  if (blockIdx.x >= GRAPHS){
    const int gid = (blockIdx.x-GRAPHS)*512 + tid;   // 48 blocks * 512 = 24576
    if (gid < 8192){                                 // EW1T
      const int t = gid>>7, c = gid&127;
      float acc=0.f;
      #pragma unroll 4
      for (int k=0;k<128;k++) acc += emb[t*128+k]*W1[k*128+c];
      EW1T[c*64+t]=f2bf(acc);
    } else {                                         // W2T[n][k]=bf16(W2[k][n])
      const int i = gid - 8192;                      // 16384
      const int k = i>>7, n = i&127;                 // consecutive n: coalesced read
      W2T[n*128+k] = f2bf(W2[k*128+n]);
    }
    return;
  }
  const int b=blockIdx.x, eb=b*EPG, nb=b*NPG;
  hist[tid]=0; co[tid]=0; ntype_sh[tid]=(unsigned short)ntype[nb+tid];
  __syncthreads();
  int4 d4[4], s4[4];
  {
    const int4* dv = (const int4*)(dst+eb);
    const int4* sv = (const int4*)(src+eb);
    #pragma unroll
    for (int j=0;j<4;j++){
      d4[j]=dv[tid + j*512];
      s4[j]=sv[tid + j*512];
      atomicAdd(&hist[d4[j].x&(NPG-1)],1); atomicAdd(&hist[d4[j].y&(NPG-1)],1);
      atomicAdd(&hist[d4[j].z&(NPG-1)],1); atomicAdd(&hist[d4[j].w&(NPG-1)],1);
      atomicAdd(&co[s4[j].x&(NPG-1)],1);   atomicAdd(&co[s4[j].y&(NPG-1)],1);
      atomicAdd(&co[s4[j].z&(NPG-1)],1);   atomicAdd(&co[s4[j].w&(NPG-1)],1);
    }
  }
  __syncthreads();
  if (tid<64){
    int carry=0;
    #pragma unroll
    for (int c=0;c<8;c++){
      int sc=hist[64*c+tid];
      #pragma unroll
      for (int off=1;off<64;off<<=1){ int y=__shfl_up(sc,off); if (tid>=off) sc+=y; }
      cs[64*c+tid+1]=carry+sc;
      carry+=__shfl(sc,63);
    }
    if (tid==0) cs[0]=0;
  }
  __syncthreads();
  cursor[tid]=cs[tid];
  __syncthreads();
  #pragma unroll
  for (int j=0;j<4;j++){
    int dl, s, pos;
    dl=d4[j].x&(NPG-1); s=s4[j].x&(NPG-1);
    pos=atomicAdd(&cursor[dl],1); sorted[pos]=(unsigned short)((ntype_sh[s]<<9)|s);
    dl=d4[j].y&(NPG-1); s=s4[j].y&(NPG-1);
    pos=atomicAdd(&cursor[dl],1); sorted[pos]=(unsigned short)((ntype_sh[s]<<9)|s);
    dl=d4[j].z&(NPG-1); s=s4[j].z&(NPG-1);
    pos=atomicAdd(&cursor[dl],1); sorted[pos]=(unsigned short)((ntype_sh[s]<<9)|s);
    dl=d4[j].w&(NPG-1); s=s4[j].w&(NPG-1);
    pos=atomicAdd(&cursor[dl],1); sorted[pos]=(unsigned short)((ntype_sh[s]<<9)|s);
  }
  __syncthreads();
  for (int i=tid;i<EPG/2;i+=512)
    ((unsigned int*)(sorted_g+(size_t)eb))[i] = ((const unsigned int*)sorted)[i];
  if (tid==0) start_g[b*(NPG+1)+NPG]=cs[NPG];
  start_g[b*(NPG+1)+tid]=cs[tid];
  {
    int a=co[tid]; if(a<1)a=1;
    out_isqrt[nb+tid]=rsqrtf((float)a);
  }
}

// ---------- layer-1: S-histogram + MFMA(S_hi/lo @ EW1) ----------------------
// block = (graph, half: 256 dst rows), 512 thr. Output h1 in MFMA-B-fragment
// order (R13 win): offset = (((b*16+ks)*8+ct)*64 + q2*16 + l16)*8 + j.
// value = relu(agg*in_isqrt + b1) * out_isqrt  (bf16)
#define A1_LDS 73232   // S f32[256][68] | wsc[512] | sstart[257] | bsh[128]
__global__ __launch_bounds__(512) void k_agg1(
      const unsigned short* __restrict__ sorted_g, const int* __restrict__ start_g,
      const unsigned short* __restrict__ EW1T, const float* __restrict__ out_isqrt,
      const float* __restrict__ b1, unsigned short* __restrict__ h1F){
  extern __shared__ char smem[];
  float* S      = (float*)(smem);               // [256][68]
  float* wsc    = (float*)(smem + 69632);       // [512]
  int*   sstart = (int*)  (smem + 71680);       // [257]
  float* bsh    = (float*)(smem + 72720);       // [128]
  const int bid=blockIdx.x, b=bid>>1, half=bid&1;
  const int v0=half*256, nb=b*NPG, tid=threadIdx.x;
  for (int i=tid; i<(256*68)/4; i+=512) ((f32x4*)S)[i]=(f32x4){0.f,0.f,0.f,0.f};
  for (int i=tid; i<NPG; i+=512) wsc[i]=out_isqrt[nb+i];
  for (int i=tid; i<257; i+=512) sstart[i]=start_g[b*(NPG+1)+v0+i];
  if (tid<128) bsh[tid]=b1[tid];
  __syncthreads();
  if (tid<256){                                 // thread-per-dst scatter
    const int beg=sstart[tid], end=sstart[tid+1];
    float* Sd = S + tid*68;
    const unsigned short* sg = sorted_g + (size_t)b*EPG;
    for (int i=beg;i<end;++i){
      const int ent = sg[i];
      Sd[ent>>9] += wsc[ent&511];
    }
  }
  __syncthreads();
  const int wave=tid>>6, lane=tid&63, l16=lane&15, quad=lane>>4;
  f32x4 acc[2][8];
  #pragma unroll
  for (int rt=0;rt<2;rt++)
    #pragma unroll
    for (int nt=0;nt<8;nt++) acc[rt][nt]=(f32x4){0.f,0.f,0.f,0.f};
  #pragma unroll
  for (int ks=0; ks<4; ++ks){                   // ks 0,1 = hi; 2,3 = lo
    const int kc = (ks&1)*32 + quad*8;
    s16x8 a[2];
    #pragma unroll
    for (int rt=0;rt<2;rt++){
      const int m = (wave*2+rt)*16 + l16;
      const float* sp = &S[m*68 + kc];
      f32x4 va = *(const f32x4*)sp;
      f32x4 vb = *(const f32x4*)(sp+4);
      union { s16x8 v; unsigned short u[8]; } pk;
      #pragma unroll
      for (int j=0;j<8;j++){
        const float f = (j<4)? va[j] : vb[j-4];
        const unsigned short hi = f2bf(f);
        pk.u[j] = (ks<2) ? hi : f2bf(f - bf2f(hi));
      }
      a[rt]=pk.v;
    }
    #pragma unroll
    for (int nt=0;nt<8;nt++){
      s16x8 bfr=__builtin_bit_cast(s16x8,
          *(const uint4*)(EW1T + (size_t)(nt*16+l16)*64 + kc));
      #pragma unroll
      for (int rt=0;rt<2;rt++)
        acc[rt][nt]=__builtin_amdgcn_mfma_f32_16x16x32_bf16(a[rt],bfr,acc[rt][nt],0,0,0);
    }
  }
  #pragma unroll
  for (int rt=0;rt<2;rt++){
    const int W = wave*2+rt;                    // m-tile in [0,16) within half
    const int mloc = W*16 + quad*4;
    float isq[4], os[4];
    #pragma unroll
    for (int r=0;r<4;r++){
      int d = sstart[mloc+r+1]-sstart[mloc+r]; if (d<1) d=1;
      isq[r]=rsqrtf((float)d);
      os[r]=wsc[v0+mloc+r];
    }
    const int ks2 = half*8 + (W>>1);
    const int q2  = ((W&1)<<1) | (quad>>1);
    const int j0  = (quad&1)*4;
    #pragma unroll
    for (int nt=0;nt<8;nt++){
      const int col = nt*16+l16;
      const float bb = bsh[col];
      ushort4 st;
      float v;
      v = fmaxf(acc[rt][nt][0]*isq[0]+bb,0.f)*os[0]; st.x=f2bf(v);
      v = fmaxf(acc[rt][nt][1]*isq[1]+bb,0.f)*os[1]; st.y=f2bf(v);
      v = fmaxf(acc[rt][nt][2]*isq[2]+bb,0.f)*os[2]; st.z=f2bf(v);
      v = fmaxf(acc[rt][nt][3]*isq[3]+bb,0.f)*os[3]; st.w=f2bf(v);
      const size_t off = ((((size_t)b*16 + ks2)*8 + nt)*64 + q2*16 + l16)*8 + j0;
      *(ushort4*)(h1F + off) = st;
    }
  }
}

// ---------- layer-2: A(u8 counts) @ h1F via MFMA -> M1F (R14, unchanged) ----
#define A2_LDS 67080   // A u8[128][520] | sstart[129]
__global__ __launch_bounds__(512) void k_agg2(
      const unsigned short* __restrict__ sorted_g, const int* __restrict__ start_g,
      const unsigned short* __restrict__ h1F, unsigned short* __restrict__ M1F){
  extern __shared__ char smem[];
  unsigned char* A = (unsigned char*)smem;      // [128][520]
  unsigned int* A32 = (unsigned int*)smem;
  int* sstart = (int*)(smem + 66560);           // [129]
  const int bid=blockIdx.x;
  const int b  = ((bid>>5)<<3) | (bid&7);       // graph (XCD swizzle)
  const int dt = (bid>>3)&3;                    // dst tile
  const int v0=dt*128, tid=threadIdx.x;
  for (int i=tid; i<66560/16; i+=512) ((uint4*)smem)[i]=(uint4){0u,0u,0u,0u};
  for (int i=tid; i<129; i+=512) sstart[i]=start_g[b*(NPG+1)+v0+i];
  __syncthreads();
  {                                             // parallel count scatter: 4 thr/dst
    const int d = tid>>2, q = tid&3;
    const int beg=sstart[d], end=sstart[d+1], len=end-beg;
    const int qb = beg + ((len*q)>>2), qe = beg + ((len*(q+1))>>2);
    const unsigned short* sg = sorted_g + (size_t)b*EPG;
    const int rowbase = d*130;
    for (int i=qb;i<qe;++i){
      const int s = sg[i]&511;
      atomicAdd(&A32[rowbase + (s>>2)], 1u<<((s&3)*8));
    }
  }
  __syncthreads();
  const int wave=tid>>6, lane=tid&63, l16=lane&15, quad=lane>>4;
  const int mg=wave>>1, ng=wave&1;              // 8 m-tiles x 8 n-tiles total
  f32x4 acc[2][4];
  #pragma unroll
  for (int rt=0;rt<2;rt++)
    #pragma unroll
    for (int ct=0;ct<4;ct++) acc[rt][ct]=(f32x4){0.f,0.f,0.f,0.f};
  const uint4* bp[4];                           // coalesced fragment pointers
  #pragma unroll
  for (int ct=0;ct<4;ct++)
    bp[ct] = (const uint4*)h1F + (((size_t)b*16)*8 + (ng*4+ct))*64 + lane;
  const unsigned char* Ab[2];
  #pragma unroll
  for (int rt=0;rt<2;rt++)
    Ab[rt] = A + ((mg*2+rt)*16 + l16)*520 + quad*8;
  #pragma unroll 2
  for (int ks=0; ks<16; ++ks){
    uint4 bq[4];
    #pragma unroll
    for (int ct=0;ct<4;ct++) bq[ct] = bp[ct][(size_t)ks*512];
    s16x8 afr[2];
    #pragma unroll
    for (int rt=0;rt<2;rt++){
      const uint2 aw = *(const uint2*)(Ab[rt] + ks*32);
      union { s16x8 v; unsigned short u[8]; } pk;
      #pragma unroll
      for (int j=0;j<4;j++){
        const float f0 = (float)((aw.x>>(8*j))&0xffu);   // exact small ints
        const float f1 = (float)((aw.y>>(8*j))&0xffu);
        pk.u[j]   = (unsigned short)(__builtin_bit_cast(unsigned int, f0)>>16);
        pk.u[j+4] = (unsigned short)(__builtin_bit_cast(unsigned int, f1)>>16);
      }
      afr[rt]=pk.v;
    }
    #pragma unroll
    for (int rt=0;rt<2;rt++)
      #pragma unroll
      for (int ct=0;ct<4;ct++)
        acc[rt][ct]=__builtin_amdgcn_mfma_f32_16x16x32_bf16(afr[rt],
            __builtin_bit_cast(s16x8, bq[ct]), acc[rt][ct],0,0,0);
  }
  #pragma unroll
  for (int rt=0;rt<2;rt++){
    const int mloc=(mg*2+rt)*16 + quad*4;
    const int M = dt*8 + mg*2 + rt;
    float isq[4];
    #pragma unroll
    for (int r=0;r<4;r++){
      int d=sstart[mloc+r+1]-sstart[mloc+r]; if (d<1) d=1;
      isq[r]=rsqrtf((float)d);
    }
    #pragma unroll
    for (int ct=0;ct<4;ct++){
      const int ks2   = ng*2 + (ct>>1);
      const int quad2 = ((ct&1)<<1) | (l16>>3);
      const int j     = l16&7;
      unsigned short* base = M1F
          + ((((size_t)b*32+M)*4+ks2)*64 + quad2*16)*8 + j;
      #pragma unroll
      for (int r=0;r<4;r++)
        base[(size_t)(quad*4+r)*8] = f2bf(acc[rt][ct][r]*isq[r]);
    }
  }
}

// ---------- final GEMM: relu(M1F @ W2 + b2), fused per-graph mean -> out ----
// W2T pre-converted bf16 [n][k]: staging is 2048 aligned uint4 copies.
__global__ __launch_bounds__(512) void k_gemm2(const unsigned short* __restrict__ M1F,
      const unsigned short* __restrict__ W2T, const float* __restrict__ b2,
      float* __restrict__ out){
  __shared__ __align__(16) unsigned short WT[128][136];  // WT[n][k]
  __shared__ float bsh[128];
  __shared__ float colpart[8][128];
  const int b=blockIdx.x, tid=threadIdx.x;
  for (int idx=tid; idx<2048; idx+=512){        // 128 rows x 16 uint4
    const int row = idx>>4, c8 = idx&15;
    *(uint4*)&WT[row][c8*8] = *(const uint4*)(W2T + row*128 + c8*8);
  }
  if (tid<128) bsh[tid]=b2[tid];
  __syncthreads();
  const int wave=tid>>6, lane=tid&63, l16=lane&15, quad=lane>>4;
  float p[8];
  #pragma unroll
  for (int i=0;i<8;i++) p[i]=0.f;
  for (int chunk=0; chunk<2; ++chunk){
    f32x4 acc[2][8];
    #pragma unroll
    for (int rt=0;rt<2;rt++)
      #pragma unroll
      for (int ct=0;ct<8;ct++) acc[rt][ct]=(f32x4){0.f,0.f,0.f,0.f};
    #pragma unroll
    for (int ks=0;ks<4;ks++){
      s16x8 a[2], bf[8];
      #pragma unroll
      for (int rt=0;rt<2;rt++){
        const int M = wave*4 + chunk*2 + rt;
        a[rt]=__builtin_bit_cast(s16x8, *(const uint4*)(M1F
            + ((((size_t)b*32+M)*4+ks)*64 + lane)*8));
      }
      #pragma unroll
      for (int ct=0;ct<8;ct++)
        bf[ct]=__builtin_bit_cast(s16x8, *(const uint4*)&WT[ct*16+l16][ks*32+quad*8]);
      #pragma unroll
      for (int rt=0;rt<2;rt++)
        #pragma unroll
        for (int ct=0;ct<8;ct++)
          acc[rt][ct]=__builtin_amdgcn_mfma_f32_16x16x32_bf16(a[rt],bf[ct],acc[rt][ct],0,0,0);
    }
    #pragma unroll
    for (int rt=0;rt<2;rt++)
      #pragma unroll
      for (int ct=0;ct<8;ct++)
        #pragma unroll
        for (int r=0;r<4;r++){
          const int col=ct*16+l16;
          p[ct] += fmaxf(acc[rt][ct][r]+bsh[col],0.f);
        }
  }
  #pragma unroll
  for (int ct=0;ct<8;ct++){
    p[ct] += __shfl_xor(p[ct],16);
    p[ct] += __shfl_xor(p[ct],32);
  }
  if (quad==0){
    #pragma unroll
    for (int ct=0;ct<8;ct++) colpart[wave][ct*16+l16]=p[ct];
  }
  __syncthreads();
  if (tid<128){
    float s=0.f;
    #pragma unroll
    for (int w=0;w<8;w++) s+=colpart[w][tid];
    out[b*128+tid]=s*(1.f/512.f);
  }
}

extern "C" void kernel_launch(void* const* d_in, const int* in_sizes, int n_in,
                              void* d_out, int out_size, void* d_ws, size_t ws_size,
                              hipStream_t stream){
  const int* node_feat = (const int*)d_in[0];
  const int* src = (const int*)d_in[1];
  const int* dst = (const int*)d_in[2];
  const float* emb = (const float*)d_in[3];
  const float* W1  = (const float*)d_in[4];
  const float* b1  = (const float*)d_in[5];
  const float* W2  = (const float*)d_in[6];
  const float* b2  = (const float*)d_in[7];

  char* ws = (char*)d_ws;
  float* out_isqrt        = (float*)(ws);                          // 524288 B
  int* start_g            = (int*)(ws + 524288);                   // 525312 B
  unsigned short* sorted_g= (unsigned short*)(ws + 1049600);       // 4194304 B
  unsigned short* EW1T    = (unsigned short*)(ws + 5243904);       // 16384 B
  unsigned short* W2T     = (unsigned short*)(ws + 5260288);       // 32768 B
  unsigned short* h1F     = (unsigned short*)(ws + 5293056);       // 33554432 B
  unsigned short* M1F     = (unsigned short*)(ws + 38847488);      // 33554432 B

  (void)hipFuncSetAttribute(reinterpret_cast<const void*>(&k_agg1),
        hipFuncAttributeMaxDynamicSharedMemorySize, A1_LDS);
  (void)hipFuncSetAttribute(reinterpret_cast<const void*>(&k_agg2),
        hipFuncAttributeMaxDynamicSharedMemorySize, A2_LDS);

  k_csr<<<GRAPHS+48,512,0,stream>>>(src,dst,node_feat,emb,W1,W2,
        sorted_g,start_g,out_isqrt,EW1T,W2T);
  k_agg1<<<GRAPHS*2,512,A1_LDS,stream>>>(sorted_g,start_g,EW1T,out_isqrt,b1,h1F);
  k_agg2<<<GRAPHS*4,512,A2_LDS,stream>>>(sorted_g,start_g,h1F,M1F);
  k_gemm2<<<GRAPHS,512,0,stream>>>(M1F,W2T,b2,(float*)d_out);
}

// Round 18
// 148.734 us; speedup vs baseline: 1.0529x; 1.0162x over previous
//
#include <hip/hip_runtime.h>
#include <stdint.h>

#define GRAPHS 256
#define NPG    512
#define EPG    8192
#define NTOT   (GRAPHS*NPG)

typedef __attribute__((ext_vector_type(8))) short s16x8;
typedef __attribute__((ext_vector_type(4))) float f32x4;

__device__ __forceinline__ float bf2f(unsigned short u){
  union { unsigned int i; float f; } c; c.i = ((unsigned int)u)<<16; return c.f;
}
__device__ __forceinline__ unsigned short f2bf(float f){
  union { float f; unsigned int i; } c; c.f = f;
  unsigned int r = c.i + 0x7fffu + ((c.i>>16)&1u);   // RNE
  return (unsigned short)(r>>16);
}

// ---------- CSR build + out_isqrt (blocks 0..255) ; prep (256..303) ---------
// sorted entry now u32: (d<<15)|(t<<9)|s  -> enables edge-parallel scatters.
__global__ __launch_bounds__(512) void k_csr(const int* __restrict__ src,
      const int* __restrict__ dst, const int* __restrict__ ntype,
      const float* __restrict__ emb, const float* __restrict__ W1,
      const float* __restrict__ W2,
      unsigned int* __restrict__ sorted_g, int* __restrict__ start_g,
      float* __restrict__ out_isqrt, unsigned short* __restrict__ EW1T,
      unsigned short* __restrict__ W2T){
  __shared__ int hist[NPG], cursor[NPG], co[NPG], cs[NPG+1];
  __shared__ unsigned short ntype_sh[NPG];
  __shared__ unsigned int sorted[EPG];
  const int tid=threadIdx.x;
  if (blockIdx.x >= GRAPHS){
    const int gid = (blockIdx.x-GRAPHS)*512 + tid;   // 48 blocks * 512 = 24576
    if (gid < 8192){                                 // EW1T
      const int t = gid>>7, c = gid&127;
      float acc=0.f;
      #pragma unroll 4
      for (int k=0;k<128;k++) acc += emb[t*128+k]*W1[k*128+c];
      EW1T[c*64+t]=f2bf(acc);
    } else {                                         // W2T[n][k]=bf16(W2[k][n])
      const int i = gid - 8192;                      // 16384
      const int k = i>>7, n = i&127;
      W2T[n*128+k] = f2bf(W2[k*128+n]);
    }
    return;
  }
  const int b=blockIdx.x, eb=b*EPG, nb=b*NPG;
  hist[tid]=0; co[tid]=0; ntype_sh[tid]=(unsigned short)ntype[nb+tid];
  __syncthreads();
  int4 d4[4], s4[4];
  {
    const int4* dv = (const int4*)(dst+eb);
    const int4* sv = (const int4*)(src+eb);
    #pragma unroll
    for (int j=0;j<4;j++){
      d4[j]=dv[tid + j*512];
      s4[j]=sv[tid + j*512];
      atomicAdd(&hist[d4[j].x&(NPG-1)],1); atomicAdd(&hist[d4[j].y&(NPG-1)],1);
      atomicAdd(&hist[d4[j].z&(NPG-1)],1); atomicAdd(&hist[d4[j].w&(NPG-1)],1);
      atomicAdd(&co[s4[j].x&(NPG-1)],1);   atomicAdd(&co[s4[j].y&(NPG-1)],1);
      atomicAdd(&co[s4[j].z&(NPG-1)],1);   atomicAdd(&co[s4[j].w&(NPG-1)],1);
    }
  }
  __syncthreads();
  if (tid<64){
    int carry=0;
    #pragma unroll
    for (int c=0;c<8;c++){
      int sc=hist[64*c+tid];
      #pragma unroll
      for (int off=1;off<64;off<<=1){ int y=__shfl_up(sc,off); if (tid>=off) sc+=y; }
      cs[64*c+tid+1]=carry+sc;
      carry+=__shfl(sc,63);
    }
    if (tid==0) cs[0]=0;
  }
  __syncthreads();
  cursor[tid]=cs[tid];
  __syncthreads();
  #pragma unroll
  for (int j=0;j<4;j++){
    int dl, s, pos;
    dl=d4[j].x&(NPG-1); s=s4[j].x&(NPG-1);
    pos=atomicAdd(&cursor[dl],1);
    sorted[pos]=((unsigned int)dl<<15)|((unsigned int)ntype_sh[s]<<9)|(unsigned int)s;
    dl=d4[j].y&(NPG-1); s=s4[j].y&(NPG-1);
    pos=atomicAdd(&cursor[dl],1);
    sorted[pos]=((unsigned int)dl<<15)|((unsigned int)ntype_sh[s]<<9)|(unsigned int)s;
    dl=d4[j].z&(NPG-1); s=s4[j].z&(NPG-1);
    pos=atomicAdd(&cursor[dl],1);
    sorted[pos]=((unsigned int)dl<<15)|((unsigned int)ntype_sh[s]<<9)|(unsigned int)s;
    dl=d4[j].w&(NPG-1); s=s4[j].w&(NPG-1);
    pos=atomicAdd(&cursor[dl],1);
    sorted[pos]=((unsigned int)dl<<15)|((unsigned int)ntype_sh[s]<<9)|(unsigned int)s;
  }
  __syncthreads();
  for (int i=tid;i<EPG;i+=512) sorted_g[(size_t)eb+i] = sorted[i];
  if (tid==0) start_g[b*(NPG+1)+NPG]=cs[NPG];
  start_g[b*(NPG+1)+tid]=cs[tid];
  {
    int a=co[tid]; if(a<1)a=1;
    out_isqrt[nb+tid]=rsqrtf((float)a);
  }
}

// ---------- layer-1: int-S histogram (edge-parallel) + MFMA(S_hi/lo @ EW1) --
// block = (graph, half: 256 dst rows), 512 thr. Scatter: all threads do
// coalesced u32 loads of the half's sorted range + native int ds_add into
// fixed-point S (wsc x 2^20; exact int adds; dequant = exponent shift).
// Output h1 in MFMA-B-fragment order (R13). value = relu(agg*isq+b1)*osc.
#define A1_LDS 75280   // Sint[256][68] | wsc f[512] | wint i[512] | sstart[257] | bsh[128]
__global__ __launch_bounds__(512) void k_agg1(
      const unsigned int* __restrict__ sorted_g, const int* __restrict__ start_g,
      const unsigned short* __restrict__ EW1T, const float* __restrict__ out_isqrt,
      const float* __restrict__ b1, unsigned short* __restrict__ h1F){
  extern __shared__ char smem[];
  int*   Sint   = (int*)(smem);                 // [256][68]
  float* wsc    = (float*)(smem + 69632);       // [512]
  int*   wint   = (int*)  (smem + 71680);       // [512]
  int*   sstart = (int*)  (smem + 73728);       // [257]
  float* bsh    = (float*)(smem + 74756);       // [128]
  const int bid=blockIdx.x, b=bid>>1, half=bid&1;
  const int v0=half*256, nb=b*NPG, tid=threadIdx.x;
  for (int i=tid; i<(256*68)/4; i+=512) ((f32x4*)Sint)[i]=(f32x4){0.f,0.f,0.f,0.f};
  for (int i=tid; i<NPG; i+=512){
    const float w = out_isqrt[nb+i];
    wsc[i]=w;
    wint[i]=(int)(w*1048576.f);                 // 2^20 fixed point
  }
  for (int i=tid; i<257; i+=512) sstart[i]=start_g[b*(NPG+1)+v0+i];
  if (tid<128) bsh[tid]=b1[tid];
  __syncthreads();
  {                                             // edge-parallel int scatter
    const int beg=sstart[0], end=sstart[256];
    const unsigned int* sg = sorted_g + (size_t)b*EPG;
    for (int i=beg+tid; i<end; i+=512){
      const unsigned int ent = sg[i];
      const int dl = (int)(ent>>15) - v0;       // in [0,256)
      const int t  = (ent>>9)&63;
      atomicAdd(&Sint[dl*68 + t], wint[ent&511]);
    }
  }
  __syncthreads();
  const int wave=tid>>6, lane=tid&63, l16=lane&15, quad=lane>>4;
  f32x4 acc[2][8];
  #pragma unroll
  for (int rt=0;rt<2;rt++)
    #pragma unroll
    for (int nt=0;nt<8;nt++) acc[rt][nt]=(f32x4){0.f,0.f,0.f,0.f};
  #pragma unroll
  for (int ks=0; ks<4; ++ks){                   // ks 0,1 = hi; 2,3 = lo
    const int kc = (ks&1)*32 + quad*8;
    s16x8 a[2];
    #pragma unroll
    for (int rt=0;rt<2;rt++){
      const int m = (wave*2+rt)*16 + l16;
      const int* sp = &Sint[m*68 + kc];
      union { s16x8 v; unsigned short u[8]; } pk;
      #pragma unroll
      for (int j=0;j<8;j++){
        const float f = (float)sp[j] * (1.f/1048576.f);  // exact exp shift
        const unsigned short hi = f2bf(f);
        pk.u[j] = (ks<2) ? hi : f2bf(f - bf2f(hi));
      }
      a[rt]=pk.v;
    }
    #pragma unroll
    for (int nt=0;nt<8;nt++){
      s16x8 bfr=__builtin_bit_cast(s16x8,
          *(const uint4*)(EW1T + (size_t)(nt*16+l16)*64 + kc));
      #pragma unroll
      for (int rt=0;rt<2;rt++)
        acc[rt][nt]=__builtin_amdgcn_mfma_f32_16x16x32_bf16(a[rt],bfr,acc[rt][nt],0,0,0);
    }
  }
  #pragma unroll
  for (int rt=0;rt<2;rt++){
    const int W = wave*2+rt;                    // m-tile in [0,16) within half
    const int mloc = W*16 + quad*4;
    float isq[4], os[4];
    #pragma unroll
    for (int r=0;r<4;r++){
      int d = sstart[mloc+r+1]-sstart[mloc+r]; if (d<1) d=1;
      isq[r]=rsqrtf((float)d);
      os[r]=wsc[v0+mloc+r];
    }
    const int ks2 = half*8 + (W>>1);
    const int q2  = ((W&1)<<1) | (quad>>1);
    const int j0  = (quad&1)*4;
    #pragma unroll
    for (int nt=0;nt<8;nt++){
      const int col = nt*16+l16;
      const float bb = bsh[col];
      ushort4 st;
      float v;
      v = fmaxf(acc[rt][nt][0]*isq[0]+bb,0.f)*os[0]; st.x=f2bf(v);
      v = fmaxf(acc[rt][nt][1]*isq[1]+bb,0.f)*os[1]; st.y=f2bf(v);
      v = fmaxf(acc[rt][nt][2]*isq[2]+bb,0.f)*os[2]; st.z=f2bf(v);
      v = fmaxf(acc[rt][nt][3]*isq[3]+bb,0.f)*os[3]; st.w=f2bf(v);
      const size_t off = ((((size_t)b*16 + ks2)*8 + nt)*64 + q2*16 + l16)*8 + j0;
      *(ushort4*)(h1F + off) = st;
    }
  }
}

// ---------- layer-2: A(u8 counts) @ h1F via MFMA -> M1F ---------------------
#define A2_LDS 67080   // A u8[128][520] | sstart[129]
__global__ __launch_bounds__(512) void k_agg2(
      const unsigned int* __restrict__ sorted_g, const int* __restrict__ start_g,
      const unsigned short* __restrict__ h1F, unsigned short* __restrict__ M1F){
  extern __shared__ char smem[];
  unsigned char* A = (unsigned char*)smem;      // [128][520]
  unsigned int* A32 = (unsigned int*)smem;
  int* sstart = (int*)(smem + 66560);           // [129]
  const int bid=blockIdx.x;
  const int b  = ((bid>>5)<<3) | (bid&7);       // graph (XCD swizzle)
  const int dt = (bid>>3)&3;                    // dst tile
  const int v0=dt*128, tid=threadIdx.x;
  for (int i=tid; i<66560/16; i+=512) ((uint4*)smem)[i]=(uint4){0u,0u,0u,0u};
  for (int i=tid; i<129; i+=512) sstart[i]=start_g[b*(NPG+1)+v0+i];
  __syncthreads();
  {                                             // edge-parallel count scatter
    const int beg=sstart[0], end=sstart[128];
    const unsigned int* sg = sorted_g + (size_t)b*EPG;
    for (int i=beg+tid; i<end; i+=512){
      const unsigned int ent = sg[i];
      const int dl = (int)(ent>>15) - v0;       // in [0,128)
      const int s  = ent&511;
      atomicAdd(&A32[dl*130 + (s>>2)], 1u<<((s&3)*8));
    }
  }
  __syncthreads();
  const int wave=tid>>6, lane=tid&63, l16=lane&15, quad=lane>>4;
  const int mg=wave>>1, ng=wave&1;              // 8 m-tiles x 8 n-tiles total
  f32x4 acc[2][4];
  #pragma unroll
  for (int rt=0;rt<2;rt++)
    #pragma unroll
    for (int ct=0;ct<4;ct++) acc[rt][ct]=(f32x4){0.f,0.f,0.f,0.f};
  const uint4* bp[4];                           // coalesced fragment pointers
  #pragma unroll
  for (int ct=0;ct<4;ct++)
    bp[ct] = (const uint4*)h1F + (((size_t)b*16)*8 + (ng*4+ct))*64 + lane;
  const unsigned char* Ab[2];
  #pragma unroll
  for (int rt=0;rt<2;rt++)
    Ab[rt] = A + ((mg*2+rt)*16 + l16)*520 + quad*8;
  #pragma unroll 2
  for (int ks=0; ks<16; ++ks){
    uint4 bq[4];
    #pragma unroll
    for (int ct=0;ct<4;ct++) bq[ct] = bp[ct][(size_t)ks*512];
    s16x8 afr[2];
    #pragma unroll
    for (int rt=0;rt<2;rt++){
      const uint2 aw = *(const uint2*)(Ab[rt] + ks*32);
      union { s16x8 v; unsigned short u[8]; } pk;
      #pragma unroll
      for (int j=0;j<4;j++){
        const float f0 = (float)((aw.x>>(8*j))&0xffu);   // exact small ints
        const float f1 = (float)((aw.y>>(8*j))&0xffu);
        pk.u[j]   = (unsigned short)(__builtin_bit_cast(unsigned int, f0)>>16);
        pk.u[j+4] = (unsigned short)(__builtin_bit_cast(unsigned int, f1)>>16);
      }
      afr[rt]=pk.v;
    }
    #pragma unroll
    for (int rt=0;rt<2;rt++)
      #pragma unroll
      for (int ct=0;ct<4;ct++)
        acc[rt][ct]=__builtin_amdgcn_mfma_f32_16x16x32_bf16(afr[rt],
            __builtin_bit_cast(s16x8, bq[ct]), acc[rt][ct],0,0,0);
  }
  #pragma unroll
  for (int rt=0;rt<2;rt++){
    const int mloc=(mg*2+rt)*16 + quad*4;
    const int M = dt*8 + mg*2 + rt;
    float isq[4];
    #pragma unroll
    for (int r=0;r<4;r++){
      int d=sstart[mloc+r+1]-sstart[mloc+r]; if (d<1) d=1;
      isq[r]=rsqrtf((float)d);
    }
    #pragma unroll
    for (int ct=0;ct<4;ct++){
      const int ks2   = ng*2 + (ct>>1);
      const int quad2 = ((ct&1)<<1) | (l16>>3);
      const int j     = l16&7;
      unsigned short* base = M1F
          + ((((size_t)b*32+M)*4+ks2)*64 + quad2*16)*8 + j;
      #pragma unroll
      for (int r=0;r<4;r++)
        base[(size_t)(quad*4+r)*8] = f2bf(acc[rt][ct][r]*isq[r]);
    }
  }
}

// ---------- final GEMM: relu(M1F @ W2 + b2), fused per-graph mean -> out ----
__global__ __launch_bounds__(512) void k_gemm2(const unsigned short* __restrict__ M1F,
      const unsigned short* __restrict__ W2T, const float* __restrict__ b2,
      float* __restrict__ out){
  __shared__ __align__(16) unsigned short WT[128][136];  // WT[n][k]
  __shared__ float bsh[128];
  __shared__ float colpart[8][128];
  const int b=blockIdx.x, tid=threadIdx.x;
  for (int idx=tid; idx<2048; idx+=512){        // 128 rows x 16 uint4
    const int row = idx>>4, c8 = idx&15;
    *(uint4*)&WT[row][c8*8] = *(const uint4*)(W2T + row*128 + c8*8);
  }
  if (tid<128) bsh[tid]=b2[tid];
  __syncthreads();
  const int wave=tid>>6, lane=tid&63, l16=lane&15, quad=lane>>4;
  float p[8];
  #pragma unroll
  for (int i=0;i<8;i++) p[i]=0.f;
  for (int chunk=0; chunk<2; ++chunk){
    f32x4 acc[2][8];
    #pragma unroll
    for (int rt=0;rt<2;rt++)
      #pragma unroll
      for (int ct=0;ct<8;ct++) acc[rt][ct]=(f32x4){0.f,0.f,0.f,0.f};
    #pragma unroll
    for (int ks=0;ks<4;ks++){
      s16x8 a[2], bf[8];
      #pragma unroll
      for (int rt=0;rt<2;rt++){
        const int M = wave*4 + chunk*2 + rt;
        a[rt]=__builtin_bit_cast(s16x8, *(const uint4*)(M1F
            + ((((size_t)b*32+M)*4+ks)*64 + lane)*8));
      }
      #pragma unroll
      for (int ct=0;ct<8;ct++)
        bf[ct]=__builtin_bit_cast(s16x8, *(const uint4*)&WT[ct*16+l16][ks*32+quad*8]);
      #pragma unroll
      for (int rt=0;rt<2;rt++)
        #pragma unroll
        for (int ct=0;ct<8;ct++)
          acc[rt][ct]=__builtin_amdgcn_mfma_f32_16x16x32_bf16(a[rt],bf[ct],acc[rt][ct],0,0,0);
    }
    #pragma unroll
    for (int rt=0;rt<2;rt++)
      #pragma unroll
      for (int ct=0;ct<8;ct++)
        #pragma unroll
        for (int r=0;r<4;r++){
          const int col=ct*16+l16;
          p[ct] += fmaxf(acc[rt][ct][r]+bsh[col],0.f);
        }
  }
  #pragma unroll
  for (int ct=0;ct<8;ct++){
    p[ct] += __shfl_xor(p[ct],16);
    p[ct] += __shfl_xor(p[ct],32);
  }
  if (quad==0){
    #pragma unroll
    for (int ct=0;ct<8;ct++) colpart[wave][ct*16+l16]=p[ct];
  }
  __syncthreads();
  if (tid<128){
    float s=0.f;
    #pragma unroll
    for (int w=0;w<8;w++) s+=colpart[w][tid];
    out[b*128+tid]=s*(1.f/512.f);
  }
}

extern "C" void kernel_launch(void* const* d_in, const int* in_sizes, int n_in,
                              void* d_out, int out_size, void* d_ws, size_t ws_size,
                              hipStream_t stream){
  const int* node_feat = (const int*)d_in[0];
  const int* src = (const int*)d_in[1];
  const int* dst = (const int*)d_in[2];
  const float* emb = (const float*)d_in[3];
  const float* W1  = (const float*)d_in[4];
  const float* b1  = (const float*)d_in[5];
  const float* W2  = (const float*)d_in[6];
  const float* b2  = (const float*)d_in[7];

  char* ws = (char*)d_ws;
  float* out_isqrt        = (float*)(ws);                          // 524288 B
  int* start_g            = (int*)(ws + 524288);                   // 525312 B
  unsigned int* sorted_g  = (unsigned int*)(ws + 1049600);         // 8388608 B
  unsigned short* EW1T    = (unsigned short*)(ws + 9438208);       // 16384 B
  unsigned short* W2T     = (unsigned short*)(ws + 9454592);       // 32768 B
  unsigned short* h1F     = (unsigned short*)(ws + 9487360);       // 33554432 B
  unsigned short* M1F     = (unsigned short*)(ws + 43041792);      // 33554432 B

  (void)hipFuncSetAttribute(reinterpret_cast<const void*>(&k_agg1),
        hipFuncAttributeMaxDynamicSharedMemorySize, A1_LDS);
  (void)hipFuncSetAttribute(reinterpret_cast<const void*>(&k_agg2),
        hipFuncAttributeMaxDynamicSharedMemorySize, A2_LDS);

  k_csr<<<GRAPHS+48,512,0,stream>>>(src,dst,node_feat,emb,W1,W2,
        sorted_g,start_g,out_isqrt,EW1T,W2T);
  k_agg1<<<GRAPHS*2,512,A1_LDS,stream>>>(sorted_g,start_g,EW1T,out_isqrt,b1,h1F);
  k_agg2<<<GRAPHS*4,512,A2_LDS,stream>>>(sorted_g,start_g,h1F,M1F);
  k_gemm2<<<GRAPHS,512,0,stream>>>(M1F,W2T,b2,(float*)d_out);
}

// Round 19
// 148.529 us; speedup vs baseline: 1.0544x; 1.0014x over previous
//
#include <hip/hip_runtime.h>
#include <stdint.h>

#define GRAPHS 256
#define NPG    512
#define EPG    8192
#define NTOT   (GRAPHS*NPG)

typedef __attribute__((ext_vector_type(8))) short s16x8;
typedef __attribute__((ext_vector_type(4))) float f32x4;

__device__ __forceinline__ float bf2f(unsigned short u){
  union { unsigned int i; float f; } c; c.i = ((unsigned int)u)<<16; return c.f;
}
__device__ __forceinline__ unsigned short f2bf(float f){
  union { float f; unsigned int i; } c; c.f = f;
  unsigned int r = c.i + 0x7fffu + ((c.i>>16)&1u);   // RNE
  return (unsigned short)(r>>16);
}

// ---------- CSR build + out_isqrt (blocks 0..255) ; prep (256..303) ---------
// sorted entry u32: (d<<15)|(t<<9)|s  -> edge-parallel scatters downstream.
__global__ __launch_bounds__(512) void k_csr(const int* __restrict__ src,
      const int* __restrict__ dst, const int* __restrict__ ntype,
      const float* __restrict__ emb, const float* __restrict__ W1,
      const float* __restrict__ W2,
      unsigned int* __restrict__ sorted_g, int* __restrict__ start_g,
      float* __restrict__ out_isqrt, unsigned short* __restrict__ EW1T,
      unsigned short* __restrict__ W2T){
  __shared__ int hist[NPG], cursor[NPG], co[NPG], cs[NPG+1];
  __shared__ unsigned short ntype_sh[NPG];
  __shared__ unsigned int sorted[EPG];
  const int tid=threadIdx.x;
  if (blockIdx.x >= GRAPHS){
    const int gid = (blockIdx.x-GRAPHS)*512 + tid;   // 48 blocks * 512 = 24576
    if (gid < 8192){                                 // EW1T
      const int t = gid>>7, c = gid&127;
      float acc=0.f;
      #pragma unroll 4
      for (int k=0;k<128;k++) acc += emb[t*128+k]*W1[k*128+c];
      EW1T[c*64+t]=f2bf(acc);
    } else {                                         // W2T[n][k]=bf16(W2[k][n])
      const int i = gid - 8192;                      // 16384
      const int k = i>>7, n = i&127;
      W2T[n*128+k] = f2bf(W2[k*128+n]);
    }
    return;
  }
  const int b=blockIdx.x, eb=b*EPG, nb=b*NPG;
  hist[tid]=0; co[tid]=0; ntype_sh[tid]=(unsigned short)ntype[nb+tid];
  __syncthreads();
  int4 d4[4], s4[4];
  {
    const int4* dv = (const int4*)(dst+eb);
    const int4* sv = (const int4*)(src+eb);
    #pragma unroll
    for (int j=0;j<4;j++){
      d4[j]=dv[tid + j*512];
      s4[j]=sv[tid + j*512];
      atomicAdd(&hist[d4[j].x&(NPG-1)],1); atomicAdd(&hist[d4[j].y&(NPG-1)],1);
      atomicAdd(&hist[d4[j].z&(NPG-1)],1); atomicAdd(&hist[d4[j].w&(NPG-1)],1);
      atomicAdd(&co[s4[j].x&(NPG-1)],1);   atomicAdd(&co[s4[j].y&(NPG-1)],1);
      atomicAdd(&co[s4[j].z&(NPG-1)],1);   atomicAdd(&co[s4[j].w&(NPG-1)],1);
    }
  }
  __syncthreads();
  if (tid<64){
    int carry=0;
    #pragma unroll
    for (int c=0;c<8;c++){
      int sc=hist[64*c+tid];
      #pragma unroll
      for (int off=1;off<64;off<<=1){ int y=__shfl_up(sc,off); if (tid>=off) sc+=y; }
      cs[64*c+tid+1]=carry+sc;
      carry+=__shfl(sc,63);
    }
    if (tid==0) cs[0]=0;
  }
  __syncthreads();
  cursor[tid]=cs[tid];
  __syncthreads();
  #pragma unroll
  for (int j=0;j<4;j++){
    int dl, s, pos;
    dl=d4[j].x&(NPG-1); s=s4[j].x&(NPG-1);
    pos=atomicAdd(&cursor[dl],1);
    sorted[pos]=((unsigned int)dl<<15)|((unsigned int)ntype_sh[s]<<9)|(unsigned int)s;
    dl=d4[j].y&(NPG-1); s=s4[j].y&(NPG-1);
    pos=atomicAdd(&cursor[dl],1);
    sorted[pos]=((unsigned int)dl<<15)|((unsigned int)ntype_sh[s]<<9)|(unsigned int)s;
    dl=d4[j].z&(NPG-1); s=s4[j].z&(NPG-1);
    pos=atomicAdd(&cursor[dl],1);
    sorted[pos]=((unsigned int)dl<<15)|((unsigned int)ntype_sh[s]<<9)|(unsigned int)s;
    dl=d4[j].w&(NPG-1); s=s4[j].w&(NPG-1);
    pos=atomicAdd(&cursor[dl],1);
    sorted[pos]=((unsigned int)dl<<15)|((unsigned int)ntype_sh[s]<<9)|(unsigned int)s;
  }
  __syncthreads();
  for (int i=tid;i<EPG;i+=512) sorted_g[(size_t)eb+i] = sorted[i];
  if (tid==0) start_g[b*(NPG+1)+NPG]=cs[NPG];
  start_g[b*(NPG+1)+tid]=cs[tid];
  {
    int a=co[tid]; if(a<1)a=1;
    out_isqrt[nb+tid]=rsqrtf((float)a);
  }
}

// ---------- layer-1: int-S histogram (edge-parallel) + MFMA(S_hi/lo @ EW1) --
// XCD-aligned swizzle: graph b's two blocks share bid%8 == b%8, matching
// csr's sorted_g writer and agg2/gemm2's h1F/M1F consumers on one XCD L2.
#define A1_LDS 75280   // Sint[256][68] | wsc f[512] | wint i[512] | sstart[257] | bsh[128]
__global__ __launch_bounds__(512) void k_agg1(
      const unsigned int* __restrict__ sorted_g, const int* __restrict__ start_g,
      const unsigned short* __restrict__ EW1T, const float* __restrict__ out_isqrt,
      const float* __restrict__ b1, unsigned short* __restrict__ h1F){
  extern __shared__ char smem[];
  int*   Sint   = (int*)(smem);                 // [256][68]
  float* wsc    = (float*)(smem + 69632);       // [512]
  int*   wint   = (int*)  (smem + 71680);       // [512]
  int*   sstart = (int*)  (smem + 73728);       // [257]
  float* bsh    = (float*)(smem + 74756);       // [128]
  const int bid=blockIdx.x;
  const int b    = ((bid>>4)<<3) | (bid&7);     // graph (XCD-aligned swizzle)
  const int half = (bid>>3)&1;
  const int v0=half*256, nb=b*NPG, tid=threadIdx.x;
  for (int i=tid; i<(256*68)/4; i+=512) ((f32x4*)Sint)[i]=(f32x4){0.f,0.f,0.f,0.f};
  for (int i=tid; i<NPG; i+=512){
    const float w = out_isqrt[nb+i];
    wsc[i]=w;
    wint[i]=(int)(w*1048576.f);                 // 2^20 fixed point
  }
  for (int i=tid; i<257; i+=512) sstart[i]=start_g[b*(NPG+1)+v0+i];
  if (tid<128) bsh[tid]=b1[tid];
  __syncthreads();
  {                                             // edge-parallel int scatter
    const int beg=sstart[0], end=sstart[256];
    const unsigned int* sg = sorted_g + (size_t)b*EPG;
    for (int i=beg+tid; i<end; i+=512){
      const unsigned int ent = sg[i];
      const int dl = (int)(ent>>15) - v0;       // in [0,256)
      const int t  = (ent>>9)&63;
      atomicAdd(&Sint[dl*68 + t], wint[ent&511]);
    }
  }
  __syncthreads();
  const int wave=tid>>6, lane=tid&63, l16=lane&15, quad=lane>>4;
  f32x4 acc[2][8];
  #pragma unroll
  for (int rt=0;rt<2;rt++)
    #pragma unroll
    for (int nt=0;nt<8;nt++) acc[rt][nt]=(f32x4){0.f,0.f,0.f,0.f};
  #pragma unroll
  for (int ks=0; ks<4; ++ks){                   // ks 0,1 = hi; 2,3 = lo
    const int kc = (ks&1)*32 + quad*8;
    s16x8 a[2];
    #pragma unroll
    for (int rt=0;rt<2;rt++){
      const int m = (wave*2+rt)*16 + l16;
      const int* sp = &Sint[m*68 + kc];
      union { s16x8 v; unsigned short u[8]; } pk;
      #pragma unroll
      for (int j=0;j<8;j++){
        const float f = (float)sp[j] * (1.f/1048576.f);  // exact exp shift
        const unsigned short hi = f2bf(f);
        pk.u[j] = (ks<2) ? hi : f2bf(f - bf2f(hi));
      }
      a[rt]=pk.v;
    }
    #pragma unroll
    for (int nt=0;nt<8;nt++){
      s16x8 bfr=__builtin_bit_cast(s16x8,
          *(const uint4*)(EW1T + (size_t)(nt*16+l16)*64 + kc));
      #pragma unroll
      for (int rt=0;rt<2;rt++)
        acc[rt][nt]=__builtin_amdgcn_mfma_f32_16x16x32_bf16(a[rt],bfr,acc[rt][nt],0,0,0);
    }
  }
  #pragma unroll
  for (int rt=0;rt<2;rt++){
    const int W = wave*2+rt;                    // m-tile in [0,16) within half
    const int mloc = W*16 + quad*4;
    float isq[4], os[4];
    #pragma unroll
    for (int r=0;r<4;r++){
      int d = sstart[mloc+r+1]-sstart[mloc+r]; if (d<1) d=1;
      isq[r]=rsqrtf((float)d);
      os[r]=wsc[v0+mloc+r];
    }
    const int ks2 = half*8 + (W>>1);
    const int q2  = ((W&1)<<1) | (quad>>1);
    const int j0  = (quad&1)*4;
    #pragma unroll
    for (int nt=0;nt<8;nt++){
      const int col = nt*16+l16;
      const float bb = bsh[col];
      ushort4 st;
      float v;
      v = fmaxf(acc[rt][nt][0]*isq[0]+bb,0.f)*os[0]; st.x=f2bf(v);
      v = fmaxf(acc[rt][nt][1]*isq[1]+bb,0.f)*os[1]; st.y=f2bf(v);
      v = fmaxf(acc[rt][nt][2]*isq[2]+bb,0.f)*os[2]; st.z=f2bf(v);
      v = fmaxf(acc[rt][nt][3]*isq[3]+bb,0.f)*os[3]; st.w=f2bf(v);
      const size_t off = ((((size_t)b*16 + ks2)*8 + nt)*64 + q2*16 + l16)*8 + j0;
      *(ushort4*)(h1F + off) = st;
    }
  }
}

// ---------- layer-2: A(u8 counts) @ h1F via MFMA -> M1F ---------------------
#define A2_LDS 67080   // A u8[128][520] | sstart[129]
__global__ __launch_bounds__(512) void k_agg2(
      const unsigned int* __restrict__ sorted_g, const int* __restrict__ start_g,
      const unsigned short* __restrict__ h1F, unsigned short* __restrict__ M1F){
  extern __shared__ char smem[];
  unsigned char* A = (unsigned char*)smem;      // [128][520]
  unsigned int* A32 = (unsigned int*)smem;
  int* sstart = (int*)(smem + 66560);           // [129]
  const int bid=blockIdx.x;
  const int b  = ((bid>>5)<<3) | (bid&7);       // graph (XCD swizzle)
  const int dt = (bid>>3)&3;                    // dst tile
  const int v0=dt*128, tid=threadIdx.x;
  for (int i=tid; i<66560/16; i+=512) ((uint4*)smem)[i]=(uint4){0u,0u,0u,0u};
  for (int i=tid; i<129; i+=512) sstart[i]=start_g[b*(NPG+1)+v0+i];
  __syncthreads();
  {                                             // edge-parallel count scatter
    const int beg=sstart[0], end=sstart[128];
    const unsigned int* sg = sorted_g + (size_t)b*EPG;
    for (int i=beg+tid; i<end; i+=512){
      const unsigned int ent = sg[i];
      const int dl = (int)(ent>>15) - v0;       // in [0,128)
      const int s  = ent&511;
      atomicAdd(&A32[dl*130 + (s>>2)], 1u<<((s&3)*8));
    }
  }
  __syncthreads();
  const int wave=tid>>6, lane=tid&63, l16=lane&15, quad=lane>>4;
  const int mg=wave>>1, ng=wave&1;              // 8 m-tiles x 8 n-tiles total
  f32x4 acc[2][4];
  #pragma unroll
  for (int rt=0;rt<2;rt++)
    #pragma unroll
    for (int ct=0;ct<4;ct++) acc[rt][ct]=(f32x4){0.f,0.f,0.f,0.f};
  const uint4* bp[4];                           // coalesced fragment pointers
  #pragma unroll
  for (int ct=0;ct<4;ct++)
    bp[ct] = (const uint4*)h1F + (((size_t)b*16)*8 + (ng*4+ct))*64 + lane;
  const unsigned char* Ab[2];
  #pragma unroll
  for (int rt=0;rt<2;rt++)
    Ab[rt] = A + ((mg*2+rt)*16 + l16)*520 + quad*8;
  #pragma unroll 2
  for (int ks=0; ks<16; ++ks){
    uint4 bq[4];
    #pragma unroll
    for (int ct=0;ct<4;ct++) bq[ct] = bp[ct][(size_t)ks*512];
    s16x8 afr[2];
    #pragma unroll
    for (int rt=0;rt<2;rt++){
      const uint2 aw = *(const uint2*)(Ab[rt] + ks*32);
      union { s16x8 v; unsigned short u[8]; } pk;
      #pragma unroll
      for (int j=0;j<4;j++){
        const float f0 = (float)((aw.x>>(8*j))&0xffu);   // exact small ints
        const float f1 = (float)((aw.y>>(8*j))&0xffu);
        pk.u[j]   = (unsigned short)(__builtin_bit_cast(unsigned int, f0)>>16);
        pk.u[j+4] = (unsigned short)(__builtin_bit_cast(unsigned int, f1)>>16);
      }
      afr[rt]=pk.v;
    }
    #pragma unroll
    for (int rt=0;rt<2;rt++)
      #pragma unroll
      for (int ct=0;ct<4;ct++)
        acc[rt][ct]=__builtin_amdgcn_mfma_f32_16x16x32_bf16(afr[rt],
            __builtin_bit_cast(s16x8, bq[ct]), acc[rt][ct],0,0,0);
  }
  #pragma unroll
  for (int rt=0;rt<2;rt++){
    const int mloc=(mg*2+rt)*16 + quad*4;
    const int M = dt*8 + mg*2 + rt;
    float isq[4];
    #pragma unroll
    for (int r=0;r<4;r++){
      int d=sstart[mloc+r+1]-sstart[mloc+r]; if (d<1) d=1;
      isq[r]=rsqrtf((float)d);
    }
    #pragma unroll
    for (int ct=0;ct<4;ct++){
      const int ks2   = ng*2 + (ct>>1);
      const int quad2 = ((ct&1)<<1) | (l16>>3);
      const int j     = l16&7;
      unsigned short* base = M1F
          + ((((size_t)b*32+M)*4+ks2)*64 + quad2*16)*8 + j;
      #pragma unroll
      for (int r=0;r<4;r++)
        base[(size_t)(quad*4+r)*8] = f2bf(acc[rt][ct][r]*isq[r]);
    }
  }
}

// ---------- final GEMM: relu(M1F @ W2 + b2), fused per-graph mean -> out ----
__global__ __launch_bounds__(512) void k_gemm2(const unsigned short* __restrict__ M1F,
      const unsigned short* __restrict__ W2T, const float* __restrict__ b2,
      float* __restrict__ out){
  __shared__ __align__(16) unsigned short WT[128][136];  // WT[n][k]
  __shared__ float bsh[128];
  __shared__ float colpart[8][128];
  const int b=blockIdx.x, tid=threadIdx.x;
  for (int idx=tid; idx<2048; idx+=512){        // 128 rows x 16 uint4
    const int row = idx>>4, c8 = idx&15;
    *(uint4*)&WT[row][c8*8] = *(const uint4*)(W2T + row*128 + c8*8);
  }
  if (tid<128) bsh[tid]=b2[tid];
  __syncthreads();
  const int wave=tid>>6, lane=tid&63, l16=lane&15, quad=lane>>4;
  float p[8];
  #pragma unroll
  for (int i=0;i<8;i++) p[i]=0.f;
  for (int chunk=0; chunk<2; ++chunk){
    f32x4 acc[2][8];
    #pragma unroll
    for (int rt=0;rt<2;rt++)
      #pragma unroll
      for (int ct=0;ct<8;ct++) acc[rt][ct]=(f32x4){0.f,0.f,0.f,0.f};
    #pragma unroll
    for (int ks=0;ks<4;ks++){
      s16x8 a[2], bf[8];
      #pragma unroll
      for (int rt=0;rt<2;rt++){
        const int M = wave*4 + chunk*2 + rt;
        a[rt]=__builtin_bit_cast(s16x8, *(const uint4*)(M1F
            + ((((size_t)b*32+M)*4+ks)*64 + lane)*8));
      }
      #pragma unroll
      for (int ct=0;ct<8;ct++)
        bf[ct]=__builtin_bit_cast(s16x8, *(const uint4*)&WT[ct*16+l16][ks*32+quad*8]);
      #pragma unroll
      for (int rt=0;rt<2;rt++)
        #pragma unroll
        for (int ct=0;ct<8;ct++)
          acc[rt][ct]=__builtin_amdgcn_mfma_f32_16x16x32_bf16(a[rt],bf[ct],acc[rt][ct],0,0,0);
    }
    #pragma unroll
    for (int rt=0;rt<2;rt++)
      #pragma unroll
      for (int ct=0;ct<8;ct++)
        #pragma unroll
        for (int r=0;r<4;r++){
          const int col=ct*16+l16;
          p[ct] += fmaxf(acc[rt][ct][r]+bsh[col],0.f);
        }
  }
  #pragma unroll
  for (int ct=0;ct<8;ct++){
    p[ct] += __shfl_xor(p[ct],16);
    p[ct] += __shfl_xor(p[ct],32);
  }
  if (quad==0){
    #pragma unroll
    for (int ct=0;ct<8;ct++) colpart[wave][ct*16+l16]=p[ct];
  }
  __syncthreads();
  if (tid<128){
    float s=0.f;
    #pragma unroll
    for (int w=0;w<8;w++) s+=colpart[w][tid];
    out[b*128+tid]=s*(1.f/512.f);
  }
}

extern "C" void kernel_launch(void* const* d_in, const int* in_sizes, int n_in,
                              void* d_out, int out_size, void* d_ws, size_t ws_size,
                              hipStream_t stream){
  const int* node_feat = (const int*)d_in[0];
  const int* src = (const int*)d_in[1];
  const int* dst = (const int*)d_in[2];
  const float* emb = (const float*)d_in[3];
  const float* W1  = (const float*)d_in[4];
  const float* b1  = (const float*)d_in[5];
  const float* W2  = (const float*)d_in[6];
  const float* b2  = (const float*)d_in[7];

  char* ws = (char*)d_ws;
  float* out_isqrt        = (float*)(ws);                          // 524288 B
  int* start_g            = (int*)(ws + 524288);                   // 525312 B
  unsigned int* sorted_g  = (unsigned int*)(ws + 1049600);         // 8388608 B
  unsigned short* EW1T    = (unsigned short*)(ws + 9438208);       // 16384 B
  unsigned short* W2T     = (unsigned short*)(ws + 9454592);       // 32768 B
  unsigned short* h1F     = (unsigned short*)(ws + 9487360);       // 33554432 B
  unsigned short* M1F     = (unsigned short*)(ws + 43041792);      // 33554432 B

  (void)hipFuncSetAttribute(reinterpret_cast<const void*>(&k_agg1),
        hipFuncAttributeMaxDynamicSharedMemorySize, A1_LDS);
  (void)hipFuncSetAttribute(reinterpret_cast<const void*>(&k_agg2),
        hipFuncAttributeMaxDynamicSharedMemorySize, A2_LDS);

  k_csr<<<GRAPHS+48,512,0,stream>>>(src,dst,node_feat,emb,W1,W2,
        sorted_g,start_g,out_isqrt,EW1T,W2T);
  k_agg1<<<GRAPHS*2,512,A1_LDS,stream>>>(sorted_g,start_g,EW1T,out_isqrt,b1,h1F);
  k_agg2<<<GRAPHS*4,512,A2_LDS,stream>>>(sorted_g,start_g,h1F,M1F);
  k_gemm2<<<GRAPHS,512,0,stream>>>(M1F,W2T,b2,(float*)d_out);
}

// Round 20
// 143.460 us; speedup vs baseline: 1.0916x; 1.0353x over previous
//
#include <hip/hip_runtime.h>
#include <stdint.h>

#define GRAPHS 256
#define NPG    512
#define EPG    8192
#define NTOT   (GRAPHS*NPG)

typedef __attribute__((ext_vector_type(8))) short s16x8;
typedef __attribute__((ext_vector_type(4))) float f32x4;

__device__ __forceinline__ float bf2f(unsigned short u){
  union { unsigned int i; float f; } c; c.i = ((unsigned int)u)<<16; return c.f;
}
__device__ __forceinline__ unsigned short f2bf(float f){
  union { float f; unsigned int i; } c; c.f = f;
  unsigned int r = c.i + 0x7fffu + ((c.i>>16)&1u);   // RNE
  return (unsigned short)(r>>16);
}

// ---------- CSR build + out_isqrt (blocks 0..255) ; prep (256..303) ---------
// prep: EW1T (emb@W1)^T bf16; W2F = W2 in MFMA-B-fragment order:
//   W2F[((ks*8+nt)*64+lane)*8+j] = bf16(W2[ks*32+(lane>>4)*8+j][nt*16+(lane&15)])
__global__ __launch_bounds__(512) void k_csr(const int* __restrict__ src,
      const int* __restrict__ dst, const int* __restrict__ ntype,
      const float* __restrict__ emb, const float* __restrict__ W1,
      const float* __restrict__ W2,
      unsigned int* __restrict__ sorted_g, int* __restrict__ start_g,
      float* __restrict__ out_isqrt, unsigned short* __restrict__ EW1T,
      unsigned short* __restrict__ W2F){
  __shared__ int hist[NPG], cursor[NPG], co[NPG], cs[NPG+1];
  __shared__ unsigned short ntype_sh[NPG];
  __shared__ unsigned int sorted[EPG];
  const int tid=threadIdx.x;
  if (blockIdx.x >= GRAPHS){
    const int gid = (blockIdx.x-GRAPHS)*512 + tid;   // 48 blocks * 512 = 24576
    if (gid < 8192){                                 // EW1T
      const int t = gid>>7, c = gid&127;
      float acc=0.f;
      #pragma unroll 4
      for (int k=0;k<128;k++) acc += emb[t*128+k]*W1[k*128+c];
      EW1T[c*64+t]=f2bf(acc);
    } else {                                         // W2F fragment order
      const int i = gid - 8192;                      // 16384
      const int ks = i>>12, nt=(i>>9)&7, lane=(i>>3)&63, j=i&7;
      const int k = ks*32 + (lane>>4)*8 + j;
      const int n = nt*16 + (lane&15);
      W2F[i] = f2bf(W2[k*128+n]);
    }
    return;
  }
  const int b=blockIdx.x, eb=b*EPG, nb=b*NPG;
  hist[tid]=0; co[tid]=0; ntype_sh[tid]=(unsigned short)ntype[nb+tid];
  __syncthreads();
  int4 d4[4], s4[4];
  {
    const int4* dv = (const int4*)(dst+eb);
    const int4* sv = (const int4*)(src+eb);
    #pragma unroll
    for (int j=0;j<4;j++){
      d4[j]=dv[tid + j*512];
      s4[j]=sv[tid + j*512];
      atomicAdd(&hist[d4[j].x&(NPG-1)],1); atomicAdd(&hist[d4[j].y&(NPG-1)],1);
      atomicAdd(&hist[d4[j].z&(NPG-1)],1); atomicAdd(&hist[d4[j].w&(NPG-1)],1);
      atomicAdd(&co[s4[j].x&(NPG-1)],1);   atomicAdd(&co[s4[j].y&(NPG-1)],1);
      atomicAdd(&co[s4[j].z&(NPG-1)],1);   atomicAdd(&co[s4[j].w&(NPG-1)],1);
    }
  }
  __syncthreads();
  if (tid<64){
    int carry=0;
    #pragma unroll
    for (int c=0;c<8;c++){
      int sc=hist[64*c+tid];
      #pragma unroll
      for (int off=1;off<64;off<<=1){ int y=__shfl_up(sc,off); if (tid>=off) sc+=y; }
      cs[64*c+tid+1]=carry+sc;
      carry+=__shfl(sc,63);
    }
    if (tid==0) cs[0]=0;
  }
  __syncthreads();
  cursor[tid]=cs[tid];
  __syncthreads();
  #pragma unroll
  for (int j=0;j<4;j++){
    int dl, s, pos;
    dl=d4[j].x&(NPG-1); s=s4[j].x&(NPG-1);
    pos=atomicAdd(&cursor[dl],1);
    sorted[pos]=((unsigned int)dl<<15)|((unsigned int)ntype_sh[s]<<9)|(unsigned int)s;
    dl=d4[j].y&(NPG-1); s=s4[j].y&(NPG-1);
    pos=atomicAdd(&cursor[dl],1);
    sorted[pos]=((unsigned int)dl<<15)|((unsigned int)ntype_sh[s]<<9)|(unsigned int)s;
    dl=d4[j].z&(NPG-1); s=s4[j].z&(NPG-1);
    pos=atomicAdd(&cursor[dl],1);
    sorted[pos]=((unsigned int)dl<<15)|((unsigned int)ntype_sh[s]<<9)|(unsigned int)s;
    dl=d4[j].w&(NPG-1); s=s4[j].w&(NPG-1);
    pos=atomicAdd(&cursor[dl],1);
    sorted[pos]=((unsigned int)dl<<15)|((unsigned int)ntype_sh[s]<<9)|(unsigned int)s;
  }
  __syncthreads();
  for (int i=tid;i<EPG;i+=512) sorted_g[(size_t)eb+i] = sorted[i];
  if (tid==0) start_g[b*(NPG+1)+NPG]=cs[NPG];
  start_g[b*(NPG+1)+tid]=cs[tid];
  {
    int a=co[tid]; if(a<1)a=1;
    out_isqrt[nb+tid]=rsqrtf((float)a);
  }
}

// ---------- layer-1 + H2: S-hist + MFMA(S@EW1) -> h1(LDS) -> MFMA(h1@W2F) ---
// block = (graph, half: 256 dst rows), 512 thr, 75 KB LDS (2 blocks/CU).
// Pass 1: fixed-point edge-parallel S, MFMA S_hi/lo @ EW1T,
//         h1 = relu(agg*isq+b1)*osc -> LDS h1sh[256][136] (aliases Sint).
// Pass 2: H2 = h1 @ W2 (A-frags from LDS, B-frags coalesced from global W2F),
//         H2F written in agg2-B-fragment order (R13 layout).
#define A1_LDS 75280   // Sint[256][68]/h1sh[256][136] | wsc | wint | sstart | bsh
__global__ __launch_bounds__(512) void k_agg1(
      const unsigned int* __restrict__ sorted_g, const int* __restrict__ start_g,
      const unsigned short* __restrict__ EW1T, const float* __restrict__ out_isqrt,
      const float* __restrict__ b1, const unsigned short* __restrict__ W2F,
      unsigned short* __restrict__ H2F){
  extern __shared__ char smem[];
  int*   Sint   = (int*)(smem);                 // [256][68]  (pass 1)
  unsigned short* h1sh = (unsigned short*)(smem); // [256][136] (pass 2 alias)
  float* wsc    = (float*)(smem + 69632);       // [512]
  int*   wint   = (int*)  (smem + 71680);       // [512]
  int*   sstart = (int*)  (smem + 73728);       // [257]
  float* bsh    = (float*)(smem + 74756);       // [128]
  const int bid=blockIdx.x;
  const int b    = ((bid>>4)<<3) | (bid&7);     // graph (XCD-aligned swizzle)
  const int half = (bid>>3)&1;
  const int v0=half*256, nb=b*NPG, tid=threadIdx.x;
  for (int i=tid; i<(256*68)/4; i+=512) ((f32x4*)Sint)[i]=(f32x4){0.f,0.f,0.f,0.f};
  for (int i=tid; i<NPG; i+=512){
    const float w = out_isqrt[nb+i];
    wsc[i]=w;
    wint[i]=(int)(w*1048576.f);                 // 2^20 fixed point
  }
  for (int i=tid; i<257; i+=512) sstart[i]=start_g[b*(NPG+1)+v0+i];
  if (tid<128) bsh[tid]=b1[tid];
  __syncthreads();
  {                                             // edge-parallel int scatter
    const int beg=sstart[0], end=sstart[256];
    const unsigned int* sg = sorted_g + (size_t)b*EPG;
    for (int i=beg+tid; i<end; i+=512){
      const unsigned int ent = sg[i];
      const int dl = (int)(ent>>15) - v0;       // in [0,256)
      const int t  = (ent>>9)&63;
      atomicAdd(&Sint[dl*68 + t], wint[ent&511]);
    }
  }
  __syncthreads();
  const int wave=tid>>6, lane=tid&63, l16=lane&15, quad=lane>>4;
  f32x4 acc[2][8];
  #pragma unroll
  for (int rt=0;rt<2;rt++)
    #pragma unroll
    for (int nt=0;nt<8;nt++) acc[rt][nt]=(f32x4){0.f,0.f,0.f,0.f};
  #pragma unroll
  for (int ks=0; ks<4; ++ks){                   // ks 0,1 = hi; 2,3 = lo
    const int kc = (ks&1)*32 + quad*8;
    s16x8 a[2];
    #pragma unroll
    for (int rt=0;rt<2;rt++){
      const int m = (wave*2+rt)*16 + l16;
      const int* sp = &Sint[m*68 + kc];
      union { s16x8 v; unsigned short u[8]; } pk;
      #pragma unroll
      for (int j=0;j<8;j++){
        const float f = (float)sp[j] * (1.f/1048576.f);  // exact exp shift
        const unsigned short hi = f2bf(f);
        pk.u[j] = (ks<2) ? hi : f2bf(f - bf2f(hi));
      }
      a[rt]=pk.v;
    }
    #pragma unroll
    for (int nt=0;nt<8;nt++){
      s16x8 bfr=__builtin_bit_cast(s16x8,
          *(const uint4*)(EW1T + (size_t)(nt*16+l16)*64 + kc));
      #pragma unroll
      for (int rt=0;rt<2;rt++)
        acc[rt][nt]=__builtin_amdgcn_mfma_f32_16x16x32_bf16(a[rt],bfr,acc[rt][nt],0,0,0);
    }
  }
  // ---- epilogue 1: h1 = relu(agg*isq+b1)*osc -> LDS (C-layout) ----
  float isq[2][4], os[2][4];
  #pragma unroll
  for (int rt=0;rt<2;rt++){
    const int mloc = (wave*2+rt)*16 + quad*4;
    #pragma unroll
    for (int r=0;r<4;r++){
      int d = sstart[mloc+r+1]-sstart[mloc+r]; if (d<1) d=1;
      isq[rt][r]=rsqrtf((float)d);
      os[rt][r]=wsc[v0+mloc+r];
    }
  }
  __syncthreads();                              // all Sint reads done
  #pragma unroll
  for (int rt=0;rt<2;rt++){
    const int mloc = (wave*2+rt)*16 + quad*4;
    #pragma unroll
    for (int nt=0;nt<8;nt++){
      const int col = nt*16+l16;
      const float bb = bsh[col];
      #pragma unroll
      for (int r=0;r<4;r++){
        const float v = fmaxf(acc[rt][nt][r]*isq[rt][r]+bb,0.f)*os[rt][r];
        h1sh[(mloc+r)*136 + col] = f2bf(v);
      }
    }
  }
  __syncthreads();
  // ---- pass 2: H2 = h1 @ W2 (K=128), B from global W2F (coalesced) ----
  f32x4 acc2[2][8];
  #pragma unroll
  for (int rt=0;rt<2;rt++)
    #pragma unroll
    for (int nt=0;nt<8;nt++) acc2[rt][nt]=(f32x4){0.f,0.f,0.f,0.f};
  #pragma unroll
  for (int ks=0; ks<4; ++ks){
    s16x8 a2[2];
    #pragma unroll
    for (int rt=0;rt<2;rt++){
      const int m = (wave*2+rt)*16 + l16;
      a2[rt]=__builtin_bit_cast(s16x8,
          *(const uint4*)(h1sh + m*136 + ks*32 + quad*8));
    }
    #pragma unroll
    for (int nt=0;nt<8;nt++){
      s16x8 bfr=__builtin_bit_cast(s16x8,
          *(const uint4*)(W2F + (size_t)(((ks*8+nt)*64)+lane)*8));
      #pragma unroll
      for (int rt=0;rt<2;rt++)
        acc2[rt][nt]=__builtin_amdgcn_mfma_f32_16x16x32_bf16(a2[rt],bfr,acc2[rt][nt],0,0,0);
    }
  }
  // ---- epilogue 2: H2F in agg2-B-fragment order (R13 remap) ----
  #pragma unroll
  for (int rt=0;rt<2;rt++){
    const int W = wave*2+rt;
    const int ks2 = half*8 + (W>>1);
    const int q2  = ((W&1)<<1) | (quad>>1);
    const int j0  = (quad&1)*4;
    #pragma unroll
    for (int nt=0;nt<8;nt++){
      ushort4 st;
      st.x=f2bf(acc2[rt][nt][0]); st.y=f2bf(acc2[rt][nt][1]);
      st.z=f2bf(acc2[rt][nt][2]); st.w=f2bf(acc2[rt][nt][3]);
      const size_t off = ((((size_t)b*16 + ks2)*8 + nt)*64 + q2*16 + l16)*8 + j0;
      *(ushort4*)(H2F + off) = st;
    }
  }
}

// ---------- layer-2: counts @ H2F, epilogue relu(acc*isq+b2) colsum ---------
// block = (graph, 128-dst tile). Output: partial[(b*4+dt)*128+col].
#define A2_LDS 67592   // A u8[128][520] (red[8][64] alias) | sstart[129] | bsh[128]
__global__ __launch_bounds__(512) void k_agg2(
      const unsigned int* __restrict__ sorted_g, const int* __restrict__ start_g,
      const unsigned short* __restrict__ H2F, const float* __restrict__ b2,
      float* __restrict__ partial){
  extern __shared__ char smem[];
  unsigned char* A = (unsigned char*)smem;      // [128][520]
  unsigned int* A32 = (unsigned int*)smem;
  float* red = (float*)smem;                    // [8][64] (alias, post-MFMA)
  int* sstart = (int*)(smem + 66560);           // [129]
  float* bsh  = (float*)(smem + 67080);         // [128]
  const int bid=blockIdx.x;
  const int b  = ((bid>>5)<<3) | (bid&7);       // graph (XCD swizzle)
  const int dt = (bid>>3)&3;                    // dst tile
  const int v0=dt*128, tid=threadIdx.x;
  for (int i=tid; i<66560/16; i+=512) ((uint4*)smem)[i]=(uint4){0u,0u,0u,0u};
  for (int i=tid; i<129; i+=512) sstart[i]=start_g[b*(NPG+1)+v0+i];
  if (tid<128) bsh[tid]=b2[tid];
  __syncthreads();
  {                                             // edge-parallel count scatter
    const int beg=sstart[0], end=sstart[128];
    const unsigned int* sg = sorted_g + (size_t)b*EPG;
    for (int i=beg+tid; i<end; i+=512){
      const unsigned int ent = sg[i];
      const int dl = (int)(ent>>15) - v0;       // in [0,128)
      const int s  = ent&511;
      atomicAdd(&A32[dl*130 + (s>>2)], 1u<<((s&3)*8));
    }
  }
  __syncthreads();
  const int wave=tid>>6, lane=tid&63, l16=lane&15, quad=lane>>4;
  const int mg=wave>>1, ng=wave&1;              // 8 m-tiles x 8 n-tiles total
  f32x4 acc[2][4];
  #pragma unroll
  for (int rt=0;rt<2;rt++)
    #pragma unroll
    for (int ct=0;ct<4;ct++) acc[rt][ct]=(f32x4){0.f,0.f,0.f,0.f};
  const uint4* bp[4];                           // coalesced fragment pointers
  #pragma unroll
  for (int ct=0;ct<4;ct++)
    bp[ct] = (const uint4*)H2F + (((size_t)b*16)*8 + (ng*4+ct))*64 + lane;
  const unsigned char* Ab[2];
  #pragma unroll
  for (int rt=0;rt<2;rt++)
    Ab[rt] = A + ((mg*2+rt)*16 + l16)*520 + quad*8;
  #pragma unroll 2
  for (int ks=0; ks<16; ++ks){
    uint4 bq[4];
    #pragma unroll
    for (int ct=0;ct<4;ct++) bq[ct] = bp[ct][(size_t)ks*512];
    s16x8 afr[2];
    #pragma unroll
    for (int rt=0;rt<2;rt++){
      const uint2 aw = *(const uint2*)(Ab[rt] + ks*32);
      union { s16x8 v; unsigned short u[8]; } pk;
      #pragma unroll
      for (int j=0;j<4;j++){
        const float f0 = (float)((aw.x>>(8*j))&0xffu);   // exact small ints
        const float f1 = (float)((aw.y>>(8*j))&0xffu);
        pk.u[j]   = (unsigned short)(__builtin_bit_cast(unsigned int, f0)>>16);
        pk.u[j+4] = (unsigned short)(__builtin_bit_cast(unsigned int, f1)>>16);
      }
      afr[rt]=pk.v;
    }
    #pragma unroll
    for (int rt=0;rt<2;rt++)
      #pragma unroll
      for (int ct=0;ct<4;ct++)
        acc[rt][ct]=__builtin_amdgcn_mfma_f32_16x16x32_bf16(afr[rt],
            __builtin_bit_cast(s16x8, bq[ct]), acc[rt][ct],0,0,0);
  }
  // epilogue: relu(acc*isq + b2) and column sums -> partial
  float p[4];
  #pragma unroll
  for (int ct=0;ct<4;ct++) p[ct]=0.f;
  #pragma unroll
  for (int rt=0;rt<2;rt++){
    const int mloc=(mg*2+rt)*16 + quad*4;
    float isq[4];
    #pragma unroll
    for (int r=0;r<4;r++){
      int d=sstart[mloc+r+1]-sstart[mloc+r]; if (d<1) d=1;
      isq[r]=rsqrtf((float)d);
    }
    #pragma unroll
    for (int ct=0;ct<4;ct++){
      const int col=ng*64 + ct*16 + l16;
      const float bb = bsh[col];
      #pragma unroll
      for (int r=0;r<4;r++)
        p[ct] += fmaxf(acc[rt][ct][r]*isq[r]+bb,0.f);
    }
  }
  #pragma unroll
  for (int ct=0;ct<4;ct++){
    p[ct] += __shfl_xor(p[ct],16);              // reduce across quad (rows)
    p[ct] += __shfl_xor(p[ct],32);
  }
  __syncthreads();                              // all A reads done; red aliases A
  if (quad==0){
    #pragma unroll
    for (int ct=0;ct<4;ct++) red[wave*64 + ct*16+l16]=p[ct];
  }
  __syncthreads();
  if (tid<128){
    const int col=tid, cg=col>>6, c6=col&63;
    float s=0.f;
    #pragma unroll
    for (int m2=0;m2<4;m2++) s += red[(m2*2+cg)*64 + c6];
    partial[(size_t)(b*4+dt)*128 + col]=s;
  }
}

// ---------- final: out[b][c] = sum_dt partial / 512 -------------------------
__global__ __launch_bounds__(256) void k_final(const float* __restrict__ partial,
      float* __restrict__ out){
  const int gid = blockIdx.x*256 + threadIdx.x;   // 32768
  const int b=gid>>7, c=gid&127;
  const float* p = partial + (size_t)(b*4)*128 + c;
  out[gid] = (p[0]+p[128]+p[256]+p[384])*(1.f/512.f);
}

extern "C" void kernel_launch(void* const* d_in, const int* in_sizes, int n_in,
                              void* d_out, int out_size, void* d_ws, size_t ws_size,
                              hipStream_t stream){
  const int* node_feat = (const int*)d_in[0];
  const int* src = (const int*)d_in[1];
  const int* dst = (const int*)d_in[2];
  const float* emb = (const float*)d_in[3];
  const float* W1  = (const float*)d_in[4];
  const float* b1  = (const float*)d_in[5];
  const float* W2  = (const float*)d_in[6];
  const float* b2  = (const float*)d_in[7];

  char* ws = (char*)d_ws;
  float* out_isqrt        = (float*)(ws);                          // 524288 B
  int* start_g            = (int*)(ws + 524288);                   // 525312 B
  unsigned int* sorted_g  = (unsigned int*)(ws + 1049600);         // 8388608 B
  unsigned short* EW1T    = (unsigned short*)(ws + 9438208);       // 16384 B
  unsigned short* W2F     = (unsigned short*)(ws + 9454592);       // 32768 B
  unsigned short* H2F     = (unsigned short*)(ws + 9487360);       // 33554432 B
  float* partial          = (float*)(ws + 43041792);               // 524288 B

  (void)hipFuncSetAttribute(reinterpret_cast<const void*>(&k_agg1),
        hipFuncAttributeMaxDynamicSharedMemorySize, A1_LDS);
  (void)hipFuncSetAttribute(reinterpret_cast<const void*>(&k_agg2),
        hipFuncAttributeMaxDynamicSharedMemorySize, A2_LDS);

  k_csr<<<GRAPHS+48,512,0,stream>>>(src,dst,node_feat,emb,W1,W2,
        sorted_g,start_g,out_isqrt,EW1T,W2F);
  k_agg1<<<GRAPHS*2,512,A1_LDS,stream>>>(sorted_g,start_g,EW1T,out_isqrt,b1,
        W2F,H2F);
  k_agg2<<<GRAPHS*4,512,A2_LDS,stream>>>(sorted_g,start_g,H2F,b2,partial);
  k_final<<<128,256,0,stream>>>(partial,(float*)d_out);
}